// Round 4
// baseline (1035.673 us; speedup 1.0000x reference)
//
#include <hip/hip_runtime.h>
#include <hip/hip_bf16.h>

typedef __hip_bfloat16 bf16;
typedef __attribute__((ext_vector_type(8))) short short8v;   // 8 bf16 = 4 VGPR (MFMA A/B frag)
typedef __attribute__((ext_vector_type(4))) float f32x4;     // MFMA C/D frag

// Problem dims
#define NB 4
#define NC 256
#define NPIX 36864          // 192*192
#define NH 192
#define NW 192
#define SW 98               // db3 subband: (192+8-6)/2+1
#define SH 98
#define SUBN 9604           // SH*SW
#define PSUB 9834496        // NB*NC*SUBN

// db3: analysis correlation kernels (pre-flipped dec filters); synthesis G0S=DEC_LO, G1S=DEC_HI
__device__ __constant__ float cH0A[6] = {  0.33267055295095688f,  0.80689150931333875f,  0.45987750211933132f, -0.13501102001039084f, -0.085441273882241486f, 0.035226291882100656f };
__device__ __constant__ float cH1A[6] = {  0.035226291882100656f, 0.085441273882241486f, -0.13501102001039084f, -0.45987750211933132f,  0.80689150931333875f, -0.33267055295095688f };
__device__ __constant__ float cG0S[6] = {  0.035226291882100656f, -0.085441273882241486f, -0.13501102001039084f, 0.45987750211933132f,  0.80689150931333875f,  0.33267055295095688f };
__device__ __constant__ float cG1S[6] = { -0.33267055295095688f,  0.80689150931333875f, -0.45987750211933132f, -0.13501102001039084f,  0.085441273882241486f, 0.035226291882100656f };

__device__ inline unsigned short bfbits(float f) {
    bf16 h = __float2bfloat16(f);
    return *reinterpret_cast<unsigned short*>(&h);
}
__device__ inline float b2f(short s) {
    return __bfloat162float(*reinterpret_cast<const bf16*>(&s));
}

// ---------------- fused analysis: row DWT + col DWT in one kernel ----------------
// grid (7 bands of 14 sub-rows, NB*NC). lo/hi stay in LDS; never touch HBM.
__global__ __launch_bounds__(256) void k_dwt(const float* __restrict__ x, bf16* __restrict__ sub) {
    int band = blockIdx.x;
    int bc = blockIdx.y;
    int ho0 = band * 14;
    int jbase = 2 * ho0 - 4;              // image row held in local row 0
    __shared__ float s_x[32][192];
    __shared__ float s_lo[32][100];
    __shared__ float s_hi[32][100];
    const float* xp = x + (size_t)bc * NPIX;
    int t = threadIdx.x;
    // load 32 image rows (zero-fill OOB)
#pragma unroll
    for (int it = 0; it < 24; ++it) {
        int e = t + 256 * it;
        int r = e / 192, cc = e % 192;
        int jg = jbase + r;
        s_x[r][cc] = (jg >= 0 && jg < NH) ? xp[(size_t)jg * NW + cc] : 0.f;
    }
    __syncthreads();
    // row DWT -> s_lo/s_hi (rows with OOB jg are zero automatically via s_x)
    for (int it = 0; it < 13; ++it) {
        int e = t + 256 * it;
        if (e < 3136) {
            int r = e / 98, wo = e % 98;
            int basec = 2 * wo - 4;
            float la = 0.f, ha = 0.f;
#pragma unroll
            for (int tp = 0; tp < 6; ++tp) {
                int j = basec + tp;
                if (j >= 0 && j < NW) {
                    float v = s_x[r][j];
                    la = fmaf(v, cH0A[tp], la);
                    ha = fmaf(v, cH1A[tp], ha);
                }
            }
            s_lo[r][wo] = la; s_hi[r][wo] = ha;
        }
    }
    __syncthreads();
    // col DWT: 14 x 98 outputs -> 4 planes
    bf16* sp = sub + (size_t)bc * SUBN;
    for (int it = 0; it < 6; ++it) {
        int e = t + 256 * it;
        if (e < 1372) {
            int ho = e / 98, wo = e % 98;
            float ll = 0.f, lh = 0.f, hl = 0.f, hh = 0.f;
#pragma unroll
            for (int tp = 0; tp < 6; ++tp) {
                float lv = s_lo[2 * ho + tp][wo];
                float hv = s_hi[2 * ho + tp][wo];
                ll = fmaf(lv, cH0A[tp], ll); lh = fmaf(lv, cH1A[tp], lh);
                hl = fmaf(hv, cH0A[tp], hl); hh = fmaf(hv, cH1A[tp], hh);
            }
            size_t o = (size_t)(ho0 + ho) * SW + wo;
            sp[o] = __float2bfloat16(ll);
            sp[(size_t)PSUB + o] = __float2bfloat16(lh);
            sp[2 * (size_t)PSUB + o] = __float2bfloat16(hl);
            sp[3 * (size_t)PSUB + o] = __float2bfloat16(hh);
        }
    }
}

// ---------------- Pass A: depthwise 3x3 (pad 1) on the 4 subband planes ----------------
// grid (PSUB/256, 4). ll,lh -> conv5 ; hl -> conv7 ; hh -> conv9
__global__ __launch_bounds__(256) void k_dwsub(const bf16* __restrict__ sub, bf16* __restrict__ csub,
                                               const float* __restrict__ w5, const float* __restrict__ w7,
                                               const float* __restrict__ w9) {
    int idx = blockIdx.x * 256 + threadIdx.x;   // over PSUB
    int pl = blockIdx.y;
    int pos = idx % SUBN;
    int bc = idx / SUBN;
    int c = bc & 255;
    int wo = pos % SW, ho = pos / SW;
    const float* wsel = (pl <= 1) ? w5 : (pl == 2 ? w7 : w9);
    const float* wp = wsel + c * 9;
    const bf16* ip = sub + (size_t)pl * PSUB + (size_t)bc * SUBN;
    float acc = 0.f;
#pragma unroll
    for (int ky = 0; ky < 3; ++ky) {
        int y = ho + ky - 1;
        if (y < 0 || y >= SH) continue;
#pragma unroll
        for (int kx = 0; kx < 3; ++kx) {
            int xw = wo + kx - 1;
            if (xw < 0 || xw >= SW) continue;
            acc = fmaf(__bfloat162float(ip[y * SW + xw]), wp[ky * 3 + kx], acc);
        }
    }
    csub[(size_t)pl * PSUB + idx] = __float2bfloat16(acc);
}

// ---------------- Pass BC: col-synth + row-synth -> qbf + qsum ----------------
// Parity trick: output row hg uses subband rows hg>>1 + {0,1,2}, taps G[2i+1-(hg&1)].
// Tile 64w x 32h; all csub reads provably in-bounds (98 = 192/2+2).
__global__ __launch_bounds__(256) void k_synth2(const bf16* __restrict__ csub,
                                                bf16* __restrict__ q, float* __restrict__ qsum) {
    int w0 = blockIdx.x * 64, h0 = blockIdx.y * 32;
    int bc = blockIdx.z;
    int jh0 = h0 >> 1, jw0 = w0 >> 1;
    __shared__ short s_c[4][18][34];
    __shared__ float s_lh[2][32][34];
    __shared__ float red[4];
    const bf16* cp = csub + (size_t)bc * SUBN;
    int t = threadIdx.x;
    // load 4 planes x 18 rows x 34 cols (as ushort2)
    for (int e = t; e < 1224; e += 256) {
        int pl = e / 306;
        int r2 = e - pl * 306;
        int r = r2 / 17, cc = r2 - r * 17;
        *reinterpret_cast<ushort2*>(&s_c[pl][r][cc * 2]) =
            *reinterpret_cast<const ushort2*>(cp + (size_t)pl * PSUB + (size_t)(jh0 + r) * SW + jw0 + cc * 2);
    }
    float ge0[3] = { cG0S[1], cG0S[3], cG0S[5] };   // even-row taps
    float go0[3] = { cG0S[0], cG0S[2], cG0S[4] };   // odd-row taps
    float ge1[3] = { cG1S[1], cG1S[3], cG1S[5] };
    float go1[3] = { cG1S[0], cG1S[2], cG1S[4] };
    __syncthreads();
    // col synthesis: 2 (lo/hi) x 32 rows x 34 cols
    for (int e = t; e < 2176; e += 256) {
        int which = e / 1088;
        int r2 = e - which * 1088;
        int hh = r2 / 34, cc = r2 - hh * 34;
        int par = (h0 + hh) & 1;
        int j0 = hh >> 1;
        float a = 0.f;
#pragma unroll
        for (int i = 0; i < 3; ++i) {
            float g0 = par ? go0[i] : ge0[i];
            float g1 = par ? go1[i] : ge1[i];
            a = fmaf(b2f(s_c[2 * which][j0 + i][cc]), g0, a);
            a = fmaf(b2f(s_c[2 * which + 1][j0 + i][cc]), g1, a);
        }
        s_lh[which][hh][cc] = a;
    }
    __syncthreads();
    // row synthesis: 32 x 64 -> q (bf16) + sum(q^2)
    float lsum = 0.f;
    bf16* qp = q + (size_t)bc * NPIX;
#pragma unroll
    for (int it = 0; it < 8; ++it) {
        int e = t + 256 * it;
        int hh = e >> 6, ww = e & 63;
        int par = ww & 1;                 // w0 is even
        int j0 = ww >> 1;
        float a = 0.f;
#pragma unroll
        for (int i = 0; i < 3; ++i) {
            float g0 = par ? go0[i] : ge0[i];
            float g1 = par ? go1[i] : ge1[i];
            a = fmaf(s_lh[0][hh][j0 + i], g0, a);
            a = fmaf(s_lh[1][hh][j0 + i], g1, a);
        }
        qp[(size_t)(h0 + hh) * NW + w0 + ww] = __float2bfloat16(a);
        lsum = fmaf(a, a, lsum);
    }
#pragma unroll
    for (int off = 32; off; off >>= 1) lsum += __shfl_down(lsum, off, 64);
    if ((t & 63) == 0) red[t >> 6] = lsum;
    __syncthreads();
    if (t == 0) atomicAdd(&qsum[bc], red[0] + red[1] + red[2] + red[3]);
}

// ---------------- transpose-convert: x [b][c][n] f32 -> xT [b][n][c] bf16 ----------------

__global__ __launch_bounds__(256) void k_xpose(const float* __restrict__ x, bf16* __restrict__ xT) {
    __shared__ float T[64][68];
    int nt = blockIdx.x, ct = blockIdx.y, b = blockIdx.z;
    int n0 = nt * 64, c0 = ct * 64;
    const float* xb = x + ((size_t)b * NC + c0) * NPIX + n0;
    int t = threadIdx.x;
    int tr = t >> 4, tc4 = (t & 15) * 4;
#pragma unroll
    for (int i = 0; i < 4; ++i) {
        int cc = tr + i * 16;
        float4 v = *reinterpret_cast<const float4*>(xb + (size_t)cc * NPIX + tc4);
        T[cc][tc4] = v.x; T[cc][tc4 + 1] = v.y; T[cc][tc4 + 2] = v.z; T[cc][tc4 + 3] = v.w;
    }
    __syncthreads();
    bf16* ob = xT + ((size_t)b * NPIX + n0) * NC + c0;
#pragma unroll
    for (int i = 0; i < 4; ++i) {
        int nn = tr + i * 16;
        ushort4 u;
        u.x = bfbits(T[tc4][nn]); u.y = bfbits(T[tc4 + 1][nn]);
        u.z = bfbits(T[tc4 + 2][nn]); u.w = bfbits(T[tc4 + 3][nn]);
        *reinterpret_cast<ushort4*>(ob + (size_t)nn * NC + tc4) = u;
    }
}

// convert qkv_w (512x256 f32) -> bf16
__global__ __launch_bounds__(256) void k_cvtw(const float* __restrict__ w, bf16* __restrict__ wb) {
    int idx = blockIdx.x * 256 + threadIdx.x;
    if (idx < 512 * 256) wb[idx] = __float2bfloat16(w[idx]);
}

// ---------------- MFMA GEMM: Out[b,o,n] = sum_c W[o,c] * xT[b,n,c]  (128x128 tile) ----------------
__global__ __launch_bounds__(256) void k_gemm_bf(const bf16* __restrict__ xT, const bf16* __restrict__ wbf,
                                                 bf16* __restrict__ outp) {
    __shared__ __align__(16) short As[128 * 64];
    __shared__ __align__(16) short Bs[128 * 64];
    int nt = blockIdx.x, ot = blockIdx.y, b = blockIdx.z;
    int n0 = nt * 128, o0 = ot * 128;
    const bf16* xb = xT + (size_t)b * NPIX * NC;
    int t = threadIdx.x;
    int wv = t >> 6, l = t & 63;
    int wr = wv >> 1, wc = wv & 1;
    f32x4 z4 = {0.f, 0.f, 0.f, 0.f};
    f32x4 acc[4][4];
#pragma unroll
    for (int m = 0; m < 4; ++m)
#pragma unroll
        for (int nf = 0; nf < 4; ++nf) acc[m][nf] = z4;
    for (int kc = 0; kc < 256; kc += 64) {
        __syncthreads();
#pragma unroll
        for (int i = 0; i < 4; ++i) {
            int blk = t + 256 * i;
            int r = blk >> 3, cb = blk & 7;
            *(short8v*)(As + blk * 8) = *(const short8v*)(wbf + (size_t)(o0 + r) * NC + kc + cb * 8);
            *(short8v*)(Bs + blk * 8) = *(const short8v*)(xb + (size_t)(n0 + r) * NC + kc + cb * 8);
        }
        __syncthreads();
#pragma unroll
        for (int kk = 0; kk < 2; ++kk) {
            short8v av[4], bv[4];
#pragma unroll
            for (int m = 0; m < 4; ++m)
                av[m] = *(const short8v*)(As + (wr * 64 + m * 16 + (l & 15)) * 64 + kk * 32 + (l >> 4) * 8);
#pragma unroll
            for (int nf = 0; nf < 4; ++nf)
                bv[nf] = *(const short8v*)(Bs + (wc * 64 + nf * 16 + (l & 15)) * 64 + kk * 32 + (l >> 4) * 8);
#pragma unroll
            for (int m = 0; m < 4; ++m)
#pragma unroll
                for (int nf = 0; nf < 4; ++nf)
                    acc[m][nf] = __builtin_amdgcn_mfma_f32_16x16x32_bf16(av[m], bv[nf], acc[m][nf], 0, 0, 0);
        }
    }
    bf16* ob = outp + (size_t)b * NC * NPIX;
#pragma unroll
    for (int m = 0; m < 4; ++m)
#pragma unroll
        for (int nf = 0; nf < 4; ++nf)
#pragma unroll
            for (int r = 0; r < 4; ++r) {
                int oo = o0 + wr * 64 + m * 16 + (l >> 4) * 4 + r;
                int nn = n0 + wc * 64 + nf * 16 + (l & 15);
                ob[(size_t)oo * NPIX + nn] = __float2bfloat16(acc[m][nf][r]);
            }
}

// ---------------- fused dw3x3 + Gram partial (MFMA) + ksum ----------------
__global__ __launch_bounds__(256) void k_gram_dw(const bf16* __restrict__ qbf, const bf16* __restrict__ kraw,
                                                 const float* __restrict__ dwW,
                                                 float* __restrict__ gpart, float* __restrict__ ksum) {
    int chunk = blockIdx.x;
    int bh = blockIdx.y; int b = bh >> 3, h = bh & 7;
    const bf16* qb = qbf + ((size_t)b * NC + h * 32) * NPIX;
    const bf16* kb = kraw + ((size_t)b * NC + h * 32) * NPIX;
    __shared__ __align__(16) short Qs[32][192];
    __shared__ __align__(16) short Ks[32][192];
    __shared__ __align__(16) short Vr[32][3][200];
    __shared__ float ksh[32];
    int t = threadIdx.x;
    int wv = t >> 6, l = t & 63;
    int mh = wv >> 1, eh = wv & 1;
    int cOwn = t >> 3, sOwn = t & 7;
    float w9[9];
#pragma unroll
    for (int i = 0; i < 9; ++i) w9[i] = dwW[(h * 32 + cOwn) * 9 + i];
    if (t < 32) ksh[t] = 0.f;
    f32x4 acc = {0.f, 0.f, 0.f, 0.f};
    float k2s = 0.f;
    for (int rr = 0; rr < 8; ++rr) {
        int row = chunk * 8 + rr;
        __syncthreads();
        for (int e = t; e < 4800; e += 256) {
            int c = e / 150; int r2 = e % 150; int dy = r2 / 50; int j = r2 % 50;
            int gr = row + dy - 1; int gc0 = -4 + 4 * j;
            ushort4 u = make_ushort4(0, 0, 0, 0);
            if (gr >= 0 && gr < NH && gc0 >= 0 && gc0 + 3 < NW)
                u = *reinterpret_cast<const ushort4*>(kb + (size_t)c * NPIX + gr * NW + gc0);
            *reinterpret_cast<ushort4*>(&Vr[c][dy][4 * j]) = u;
        }
        for (int e = t; e < 1536; e += 256) {
            int c = e / 48; int j = e % 48;
            *reinterpret_cast<ushort4*>(&Qs[c][4 * j]) =
                *reinterpret_cast<const ushort4*>(qb + (size_t)c * NPIX + row * NW + 4 * j);
        }
        __syncthreads();
#pragma unroll
        for (int i = 0; i < 24; ++i) {
            int w = sOwn + 8 * i;
            float a = 0.f;
#pragma unroll
            for (int dy = 0; dy < 3; ++dy)
#pragma unroll
                for (int dx = 0; dx < 3; ++dx)
                    a = fmaf(__bfloat162float(*reinterpret_cast<const bf16*>(&Vr[cOwn][dy][w + dx + 3])),
                             w9[dy * 3 + dx], a);
            Ks[cOwn][w] = (short)bfbits(a);
            k2s = fmaf(a, a, k2s);
        }
        __syncthreads();
#pragma unroll
        for (int kk = 0; kk < 6; ++kk) {
            short8v av = *(const short8v*)(&Qs[mh * 16 + (l & 15)][kk * 32 + (l >> 4) * 8]);
            short8v bv = *(const short8v*)(&Ks[eh * 16 + (l & 15)][kk * 32 + (l >> 4) * 8]);
            acc = __builtin_amdgcn_mfma_f32_16x16x32_bf16(av, bv, acc, 0, 0, 0);
        }
    }
    atomicAdd(&ksh[cOwn], k2s);
    __syncthreads();
    if (t < 32) atomicAdd(&ksum[b * NC + h * 32 + t], ksh[t]);
    float* gp = gpart + ((size_t)bh * 24 + chunk) * 1024;
#pragma unroll
    for (int r = 0; r < 4; ++r) {
        int d = mh * 16 + (l >> 4) * 4 + r;
        int e = eh * 16 + (l & 15);
        gp[d * 32 + e] = acc[r];
    }
}

// reduce partials + normalize + temperature + row softmax
__global__ __launch_bounds__(1024) void k_attn(const float* __restrict__ gpart, const float* __restrict__ qsum,
                                               const float* __restrict__ ksum, const float* __restrict__ temp,
                                               float* __restrict__ attn) {
    int bh = blockIdx.x;
    int b = bh >> 3, h = bh & 7;
    int t = threadIdx.x;
    int d = t >> 5, e = t & 31;
    float s = 0.f;
    for (int i = 0; i < 24; ++i) s += gpart[((size_t)bh * 24 + i) * 1024 + t];
    float rq = 1.f / fmaxf(sqrtf(qsum[b * NC + h * 32 + d]), 1e-12f);
    float rk = 1.f / fmaxf(sqrtf(ksum[b * NC + h * 32 + e]), 1e-12f);
    s *= rq * rk * temp[h];
    float m = s;
#pragma unroll
    for (int off = 16; off; off >>= 1) m = fmaxf(m, __shfl_xor(m, off, 32));
    float ex = expf(s - m);
    float sum = ex;
#pragma unroll
    for (int off = 16; off; off >>= 1) sum += __shfl_xor(sum, off, 32);
    attn[(size_t)bh * 1024 + t] = ex / sum;
}

// fold proj into attn -> bf16
__global__ __launch_bounds__(256) void k_wfold(const float* __restrict__ proj, const float* __restrict__ attn,
                                               bf16* __restrict__ wfbf) {
    int o = blockIdx.x, b = blockIdx.y;
    int t = threadIdx.x;
    int h = t >> 5, e = t & 31;
    const float* ap = attn + (size_t)(b * 8 + h) * 1024 + e;
    const float* pp = proj + o * NC + h * 32;
    float acc = 0.f;
#pragma unroll
    for (int d = 0; d < 32; ++d) acc = fmaf(pp[d], ap[d * 32], acc);
    wfbf[((size_t)b * NC + o) * NC + t] = __float2bfloat16(acc);
}

// ---------------- final: out[b,o,seg] = sum_e wf[o,e] * dw(vraw)[e,seg] ----------------
__global__ __launch_bounds__(256) void k_out_dw(const bf16* __restrict__ vraw, const bf16* __restrict__ wfbf,
                                                const float* __restrict__ dwW,
                                                float* __restrict__ out) {
    int sid = blockIdx.x;            // 576 = 192 rows x 3 segs
    int b = blockIdx.y;
    int row = sid / 3, seg = sid % 3, w0 = seg * 64;
    __shared__ __align__(16) short As[256 * 64];
    __shared__ __align__(16) short Bs[64 * 64];
    __shared__ __align__(16) short Vr[64][3][72];
    const bf16* vb = vraw + (size_t)b * NC * NPIX;
    const bf16* wb = wfbf + (size_t)b * NC * NC;
    int t = threadIdx.x;
    int wv = t >> 6, l = t & 63;
    int cOwn = t & 63;
    f32x4 z4 = {0.f, 0.f, 0.f, 0.f};
    f32x4 acc[4][4];
#pragma unroll
    for (int m = 0; m < 4; ++m)
#pragma unroll
        for (int nf = 0; nf < 4; ++nf) acc[m][nf] = z4;
    for (int kc = 0; kc < 256; kc += 64) {
        float w9[9];
#pragma unroll
        for (int i = 0; i < 9; ++i) w9[i] = dwW[(kc + cOwn) * 9 + i];
        __syncthreads();
        for (int e = t; e < 3456; e += 256) {
            int c = e / 54; int r2 = e % 54; int dy = r2 / 18; int j = r2 % 18;
            int gr = row + dy - 1; int gc0 = w0 - 4 + 4 * j;
            ushort4 u = make_ushort4(0, 0, 0, 0);
            if (gr >= 0 && gr < NH && gc0 >= 0 && gc0 + 3 < NW)
                u = *reinterpret_cast<const ushort4*>(vb + (size_t)(kc + c) * NPIX + gr * NW + gc0);
            *reinterpret_cast<ushort4*>(&Vr[c][dy][4 * j]) = u;
        }
#pragma unroll
        for (int i = 0; i < 8; ++i) {
            int blk = t + 256 * i;
            int r = blk >> 3, cb = blk & 7;
            *(short8v*)(As + blk * 8) = *(const short8v*)(wb + (size_t)r * NC + kc + cb * 8);
        }
        __syncthreads();
#pragma unroll
        for (int i = 0; i < 16; ++i) {
            int n = (t >> 6) + 4 * i;
            float a = 0.f;
#pragma unroll
            for (int dy = 0; dy < 3; ++dy)
#pragma unroll
                for (int dx = 0; dx < 3; ++dx)
                    a = fmaf(__bfloat162float(*reinterpret_cast<const bf16*>(&Vr[cOwn][dy][n + dx + 3])),
                             w9[dy * 3 + dx], a);
            Bs[n * 64 + cOwn] = (short)bfbits(a);
        }
        __syncthreads();
#pragma unroll
        for (int kk = 0; kk < 2; ++kk) {
            short8v bfr[4];
#pragma unroll
            for (int nf = 0; nf < 4; ++nf)
                bfr[nf] = *(const short8v*)(Bs + (nf * 16 + (l & 15)) * 64 + kk * 32 + (l >> 4) * 8);
#pragma unroll
            for (int m = 0; m < 4; ++m) {
                short8v av = *(const short8v*)(As + (wv * 64 + m * 16 + (l & 15)) * 64 + kk * 32 + (l >> 4) * 8);
#pragma unroll
                for (int nf = 0; nf < 4; ++nf)
                    acc[m][nf] = __builtin_amdgcn_mfma_f32_16x16x32_bf16(av, bfr[nf], acc[m][nf], 0, 0, 0);
            }
        }
    }
    float* ob = out + (size_t)b * NC * NPIX + (size_t)row * NW + w0;
#pragma unroll
    for (int m = 0; m < 4; ++m)
#pragma unroll
        for (int nf = 0; nf < 4; ++nf)
#pragma unroll
            for (int r = 0; r < 4; ++r) {
                int oo = wv * 64 + m * 16 + (l >> 4) * 4 + r;
                int nn = nf * 16 + (l & 15);
                ob[(size_t)oo * NPIX + nn] = acc[m][nf][r];
            }
}

// ---------------- launcher ----------------

extern "C" void kernel_launch(void* const* d_in, const int* in_sizes, int n_in,
                              void* d_out, int out_size, void* d_ws, size_t ws_size,
                              hipStream_t stream) {
    (void)in_sizes; (void)n_in; (void)out_size;
    const float* x      = (const float*)d_in[0];
    const float* qkv_w  = (const float*)d_in[1];
    const float* qkv_cw = (const float*)d_in[2];
    const float* w5     = (const float*)d_in[3];
    const float* w7     = (const float*)d_in[4];
    const float* w9     = (const float*)d_in[5];
    const float* projw  = (const float*)d_in[6];
    const float* temp   = (const float*)d_in[7];

    // WS: [0:78.7M] sub -> (dead) -> qbf [0:75.5M] -> (dead) -> vraw [0:75.5M]
    //     [78.7M:] smalls (wbf, qsum, ksum, gpart, attn, wfbf)
    const size_t OFF_SM    = 78675968;
    const size_t OFF_WBF   = OFF_SM;                    // 262,144
    const size_t OFF_QSUM  = OFF_SM + 262144;           // 4,096
    const size_t OFF_KSUM  = OFF_QSUM + 4096;           // 4,096
    const size_t OFF_GPART = OFF_KSUM + 4096;           // 3,145,728
    const size_t OFF_ATTN  = OFF_GPART + 3145728;       // 131,072
    const size_t OFF_WF    = OFF_ATTN + 131072;         // 524,288
    const size_t WS_NEED   = OFF_WF + 524288;           // 82,747,392
    if (ws_size < WS_NEED) return;

    char* ws = (char*)d_ws;
    bf16*  sub   = (bf16*)ws;
    bf16*  qbf   = (bf16*)ws;
    bf16*  vraw  = (bf16*)ws;
    bf16*  wbf   = (bf16*)(ws + OFF_WBF);
    float* qsum  = (float*)(ws + OFF_QSUM);
    float* ksum  = (float*)(ws + OFF_KSUM);
    float* gpart = (float*)(ws + OFF_GPART);
    float* attn  = (float*)(ws + OFF_ATTN);
    bf16*  wfbf  = (bf16*)(ws + OFF_WF);

    // OUT: csub [0:78.7M] -> (dead) -> xbf [0:75.5M] + kraw [75.5M:151M] -> final out
    bf16*  csub = (bf16*)d_out;
    bf16*  xbf  = (bf16*)d_out;
    bf16*  kraw = (bf16*)((char*)d_out + 75497472);
    float* out  = (float*)d_out;

    hipMemsetAsync(ws + OFF_QSUM, 0, 8192, stream);   // qsum + ksum

    // wavelet query path
    k_dwt<<<dim3(7, NB * NC), 256, 0, stream>>>(x, sub);
    k_dwsub<<<dim3(PSUB / 256, 4), 256, 0, stream>>>(sub, csub, w5, w7, w9);
    k_synth2<<<dim3(3, 6, NB * NC), 256, 0, stream>>>(csub, qbf, qsum);

    // shared GEMM inputs
    k_xpose<<<dim3(576, 4, NB), 256, 0, stream>>>(x, xbf);
    k_cvtw<<<512, 256, 0, stream>>>(qkv_w, wbf);

    // k path
    k_gemm_bf<<<dim3(288, 2, NB), 256, 0, stream>>>(xbf, wbf, kraw);
    k_gram_dw<<<dim3(24, 32), 256, 0, stream>>>(qbf, kraw, qkv_cw, gpart, ksum);

    k_attn<<<32, 1024, 0, stream>>>(gpart, qsum, ksum, temp, attn);
    k_wfold<<<dim3(256, NB), 256, 0, stream>>>(projw, attn, wfbf);

    // v path
    k_gemm_bf<<<dim3(288, 2, NB), 256, 0, stream>>>(xbf, wbf + 256 * 256, vraw);
    k_out_dw<<<dim3(576, NB), 256, 0, stream>>>(vraw, wfbf, qkv_cw + 256 * 9, out);
}

// Round 5
// 859.421 us; speedup vs baseline: 1.2051x; 1.2051x over previous
//
#include <hip/hip_runtime.h>
#include <hip/hip_bf16.h>

typedef __hip_bfloat16 bf16;
typedef __attribute__((ext_vector_type(8))) short short8v;   // 8 bf16 = 4 VGPR (MFMA A/B frag)
typedef __attribute__((ext_vector_type(4))) float f32x4;     // MFMA C/D frag

// Problem dims
#define NB 4
#define NC 256
#define NPIX 36864          // 192*192
#define NH 192
#define NW 192
#define SW 98               // db3 subband: (192+8-6)/2+1
#define SH 98
#define SUBN 9604           // SH*SW
#define PSUB 9834496        // NB*NC*SUBN

// db3: analysis correlation kernels (pre-flipped dec filters); synthesis G0S=DEC_LO, G1S=DEC_HI
__device__ __constant__ float cH0A[6] = {  0.33267055295095688f,  0.80689150931333875f,  0.45987750211933132f, -0.13501102001039084f, -0.085441273882241486f, 0.035226291882100656f };
__device__ __constant__ float cH1A[6] = {  0.035226291882100656f, 0.085441273882241486f, -0.13501102001039084f, -0.45987750211933132f,  0.80689150931333875f, -0.33267055295095688f };
__device__ __constant__ float cG0S[6] = {  0.035226291882100656f, -0.085441273882241486f, -0.13501102001039084f, 0.45987750211933132f,  0.80689150931333875f,  0.33267055295095688f };
__device__ __constant__ float cG1S[6] = { -0.33267055295095688f,  0.80689150931333875f, -0.45987750211933132f, -0.13501102001039084f,  0.085441273882241486f, 0.035226291882100656f };

__device__ inline unsigned short bfbits(float f) {
    bf16 h = __float2bfloat16(f);
    return *reinterpret_cast<unsigned short*>(&h);
}
__device__ inline float b2f(short s) {
    return __bfloat162float(*reinterpret_cast<const bf16*>(&s));
}

// ---------------- fused analysis: row DWT + col DWT in one kernel ----------------
// grid (7 bands of 14 sub-rows, NB*NC). lo/hi stay in LDS; never touch HBM.
__global__ __launch_bounds__(256) void k_dwt(const float* __restrict__ x, bf16* __restrict__ sub) {
    int band = blockIdx.x;
    int bc = blockIdx.y;
    int ho0 = band * 14;
    int jbase = 2 * ho0 - 4;              // image row held in local row 0
    __shared__ float s_x[32][192];
    __shared__ float s_lo[32][100];
    __shared__ float s_hi[32][100];
    const float* xp = x + (size_t)bc * NPIX;
    int t = threadIdx.x;
    // load 32 image rows (zero-fill OOB)
#pragma unroll
    for (int it = 0; it < 24; ++it) {
        int e = t + 256 * it;
        int r = e / 192, cc = e % 192;
        int jg = jbase + r;
        s_x[r][cc] = (jg >= 0 && jg < NH) ? xp[(size_t)jg * NW + cc] : 0.f;
    }
    __syncthreads();
    // row DWT -> s_lo/s_hi
    for (int it = 0; it < 13; ++it) {
        int e = t + 256 * it;
        if (e < 3136) {
            int r = e / 98, wo = e % 98;
            int basec = 2 * wo - 4;
            float la = 0.f, ha = 0.f;
#pragma unroll
            for (int tp = 0; tp < 6; ++tp) {
                int j = basec + tp;
                if (j >= 0 && j < NW) {
                    float v = s_x[r][j];
                    la = fmaf(v, cH0A[tp], la);
                    ha = fmaf(v, cH1A[tp], ha);
                }
            }
            s_lo[r][wo] = la; s_hi[r][wo] = ha;
        }
    }
    __syncthreads();
    // col DWT: 14 x 98 outputs -> 4 planes
    bf16* sp = sub + (size_t)bc * SUBN;
    for (int it = 0; it < 6; ++it) {
        int e = t + 256 * it;
        if (e < 1372) {
            int ho = e / 98, wo = e % 98;
            float ll = 0.f, lh = 0.f, hl = 0.f, hh = 0.f;
#pragma unroll
            for (int tp = 0; tp < 6; ++tp) {
                float lv = s_lo[2 * ho + tp][wo];
                float hv = s_hi[2 * ho + tp][wo];
                ll = fmaf(lv, cH0A[tp], ll); lh = fmaf(lv, cH1A[tp], lh);
                hl = fmaf(hv, cH0A[tp], hl); hh = fmaf(hv, cH1A[tp], hh);
            }
            size_t o = (size_t)(ho0 + ho) * SW + wo;
            sp[o] = __float2bfloat16(ll);
            sp[(size_t)PSUB + o] = __float2bfloat16(lh);
            sp[2 * (size_t)PSUB + o] = __float2bfloat16(hl);
            sp[3 * (size_t)PSUB + o] = __float2bfloat16(hh);
        }
    }
}

// ---------------- fused: dw3x3(subbands) + col-synth + row-synth -> qbf + qsum ----------------
// Tile 64w x 32h. Parity trick: output row hg uses conv'd rows (hg>>1)+{0,1,2},
// taps G[2i+1-(hg&1)]. Conv'd region per tile: 4 planes x 18 rows x 34 cols,
// computed in-LDS from raw sub staged with a 1-halo (20 x 38, ushort2 loads).
__global__ __launch_bounds__(256) void k_synth2(const bf16* __restrict__ sub,
                                                const float* __restrict__ w5, const float* __restrict__ w7,
                                                const float* __restrict__ w9,
                                                bf16* __restrict__ q, float* __restrict__ qsum) {
    int w0 = blockIdx.x * 64, h0 = blockIdx.y * 32;
    int bc = blockIdx.z;
    int c = bc & 255;
    int jh0 = h0 >> 1, jw0 = w0 >> 1;
    __shared__ short s_sub[4][20][38];   // raw sub + halo: rows jh0-1.., cols jw0-2..
    __shared__ float s_c[4][18][34];     // conv'd
    __shared__ float s_lh[2][32][34];
    __shared__ float s_w[4][9];
    __shared__ float red[4];
    const bf16* sp = sub + (size_t)bc * SUBN;
    int t = threadIdx.x;
    if (t < 36) {
        int f = t / 9, k = t - f * 9;
        const float* wsel = (f <= 1) ? w5 : (f == 2 ? w7 : w9);
        s_w[f][k] = wsel[c * 9 + k];
    }
    // stage raw sub: 4 planes x 20 rows x 19 ushort2 (cols jw0-2 .. jw0+35)
    for (int e = t; e < 1520; e += 256) {
        int pl = e / 380;
        int r2 = e - pl * 380;
        int r = r2 / 19, j = r2 - r * 19;
        int gr = jh0 - 1 + r;
        int gc = jw0 - 2 + 2 * j;
        ushort2 u = make_ushort2(0, 0);
        if (gr >= 0 && gr < SH && gc >= 0 && gc < 97)
            u = *reinterpret_cast<const ushort2*>(sp + (size_t)pl * PSUB + (size_t)gr * SW + gc);
        *reinterpret_cast<ushort2*>(&s_sub[pl][r][2 * j]) = u;
    }
    float ge0[3] = { cG0S[1], cG0S[3], cG0S[5] };   // even-parity taps
    float go0[3] = { cG0S[0], cG0S[2], cG0S[4] };   // odd-parity taps
    float ge1[3] = { cG1S[1], cG1S[3], cG1S[5] };
    float go1[3] = { cG1S[0], cG1S[2], cG1S[4] };
    __syncthreads();
    // depthwise 3x3 (zero-pad handled by staged zeros): 4 x 18 x 34
    for (int e = t; e < 2448; e += 256) {
        int pl = e / 612;
        int r2 = e - pl * 612;
        int r = r2 / 34, cc = r2 - r * 34;
        const float* wp = s_w[pl];
        float a = 0.f;
#pragma unroll
        for (int ky = 0; ky < 3; ++ky)
#pragma unroll
            for (int kx = 0; kx < 3; ++kx)
                a = fmaf(b2f(s_sub[pl][r + ky][cc + 1 + kx]), wp[ky * 3 + kx], a);
        s_c[pl][r][cc] = a;
    }
    __syncthreads();
    // col synthesis: 2 (lo/hi) x 32 rows x 34 cols
    for (int e = t; e < 2176; e += 256) {
        int which = e / 1088;
        int r2 = e - which * 1088;
        int hh = r2 / 34, cc = r2 - hh * 34;
        int par = hh & 1;                 // h0 is even
        int j0 = hh >> 1;
        float a = 0.f;
#pragma unroll
        for (int i = 0; i < 3; ++i) {
            float g0 = par ? go0[i] : ge0[i];
            float g1 = par ? go1[i] : ge1[i];
            a = fmaf(s_c[2 * which][j0 + i][cc], g0, a);
            a = fmaf(s_c[2 * which + 1][j0 + i][cc], g1, a);
        }
        s_lh[which][hh][cc] = a;
    }
    __syncthreads();
    // row synthesis: 32 x 64 -> q (bf16) + sum(q^2)
    float lsum = 0.f;
    bf16* qp = q + (size_t)bc * NPIX;
#pragma unroll
    for (int it = 0; it < 8; ++it) {
        int e = t + 256 * it;
        int hh = e >> 6, ww = e & 63;
        int par = ww & 1;                 // w0 is even
        int j0 = ww >> 1;
        float a = 0.f;
#pragma unroll
        for (int i = 0; i < 3; ++i) {
            float g0 = par ? go0[i] : ge0[i];
            float g1 = par ? go1[i] : ge1[i];
            a = fmaf(s_lh[0][hh][j0 + i], g0, a);
            a = fmaf(s_lh[1][hh][j0 + i], g1, a);
        }
        qp[(size_t)(h0 + hh) * NW + w0 + ww] = __float2bfloat16(a);
        lsum = fmaf(a, a, lsum);
    }
#pragma unroll
    for (int off = 32; off; off >>= 1) lsum += __shfl_down(lsum, off, 64);
    if ((t & 63) == 0) red[t >> 6] = lsum;
    __syncthreads();
    if (t == 0) atomicAdd(&qsum[bc], red[0] + red[1] + red[2] + red[3]);
}

// ---------------- transpose-convert: x [b][c][n] f32 -> xT [b][n][c] bf16 ----------------

__global__ __launch_bounds__(256) void k_xpose(const float* __restrict__ x, bf16* __restrict__ xT) {
    __shared__ float T[64][68];
    int nt = blockIdx.x, ct = blockIdx.y, b = blockIdx.z;
    int n0 = nt * 64, c0 = ct * 64;
    const float* xb = x + ((size_t)b * NC + c0) * NPIX + n0;
    int t = threadIdx.x;
    int tr = t >> 4, tc4 = (t & 15) * 4;
#pragma unroll
    for (int i = 0; i < 4; ++i) {
        int cc = tr + i * 16;
        float4 v = *reinterpret_cast<const float4*>(xb + (size_t)cc * NPIX + tc4);
        T[cc][tc4] = v.x; T[cc][tc4 + 1] = v.y; T[cc][tc4 + 2] = v.z; T[cc][tc4 + 3] = v.w;
    }
    __syncthreads();
    bf16* ob = xT + ((size_t)b * NPIX + n0) * NC + c0;
#pragma unroll
    for (int i = 0; i < 4; ++i) {
        int nn = tr + i * 16;
        ushort4 u;
        u.x = bfbits(T[tc4][nn]); u.y = bfbits(T[tc4 + 1][nn]);
        u.z = bfbits(T[tc4 + 2][nn]); u.w = bfbits(T[tc4 + 3][nn]);
        *reinterpret_cast<ushort4*>(ob + (size_t)nn * NC + tc4) = u;
    }
}

// convert qkv_w (512x256 f32) -> bf16
__global__ __launch_bounds__(256) void k_cvtw(const float* __restrict__ w, bf16* __restrict__ wb) {
    int idx = blockIdx.x * 256 + threadIdx.x;
    if (idx < 512 * 256) wb[idx] = __float2bfloat16(w[idx]);
}

// ---------------- MFMA GEMM: Out[b,o,n] = sum_c W[o,c] * xT[b,n,c]  (128x128 tile) ----------------
__global__ __launch_bounds__(256) void k_gemm_bf(const bf16* __restrict__ xT, const bf16* __restrict__ wbf,
                                                 bf16* __restrict__ outp) {
    __shared__ __align__(16) short As[128 * 64];
    __shared__ __align__(16) short Bs[128 * 64];
    int nt = blockIdx.x, ot = blockIdx.y, b = blockIdx.z;
    int n0 = nt * 128, o0 = ot * 128;
    const bf16* xb = xT + (size_t)b * NPIX * NC;
    int t = threadIdx.x;
    int wv = t >> 6, l = t & 63;
    int wr = wv >> 1, wc = wv & 1;
    f32x4 z4 = {0.f, 0.f, 0.f, 0.f};
    f32x4 acc[4][4];
#pragma unroll
    for (int m = 0; m < 4; ++m)
#pragma unroll
        for (int nf = 0; nf < 4; ++nf) acc[m][nf] = z4;
    for (int kc = 0; kc < 256; kc += 64) {
        __syncthreads();
#pragma unroll
        for (int i = 0; i < 4; ++i) {
            int blk = t + 256 * i;
            int r = blk >> 3, cb = blk & 7;
            *(short8v*)(As + blk * 8) = *(const short8v*)(wbf + (size_t)(o0 + r) * NC + kc + cb * 8);
            *(short8v*)(Bs + blk * 8) = *(const short8v*)(xb + (size_t)(n0 + r) * NC + kc + cb * 8);
        }
        __syncthreads();
#pragma unroll
        for (int kk = 0; kk < 2; ++kk) {
            short8v av[4], bv[4];
#pragma unroll
            for (int m = 0; m < 4; ++m)
                av[m] = *(const short8v*)(As + (wr * 64 + m * 16 + (l & 15)) * 64 + kk * 32 + (l >> 4) * 8);
#pragma unroll
            for (int nf = 0; nf < 4; ++nf)
                bv[nf] = *(const short8v*)(Bs + (wc * 64 + nf * 16 + (l & 15)) * 64 + kk * 32 + (l >> 4) * 8);
#pragma unroll
            for (int m = 0; m < 4; ++m)
#pragma unroll
                for (int nf = 0; nf < 4; ++nf)
                    acc[m][nf] = __builtin_amdgcn_mfma_f32_16x16x32_bf16(av[m], bv[nf], acc[m][nf], 0, 0, 0);
        }
    }
    bf16* ob = outp + (size_t)b * NC * NPIX;
#pragma unroll
    for (int m = 0; m < 4; ++m)
#pragma unroll
        for (int nf = 0; nf < 4; ++nf)
#pragma unroll
            for (int r = 0; r < 4; ++r) {
                int oo = o0 + wr * 64 + m * 16 + (l >> 4) * 4 + r;
                int nn = n0 + wc * 64 + nf * 16 + (l & 15);
                ob[(size_t)oo * NPIX + nn] = __float2bfloat16(acc[m][nf][r]);
            }
}

// ---------------- fused dw3x3 + Gram partial (MFMA) + ksum ----------------
__global__ __launch_bounds__(256) void k_gram_dw(const bf16* __restrict__ qbf, const bf16* __restrict__ kraw,
                                                 const float* __restrict__ dwW,
                                                 float* __restrict__ gpart, float* __restrict__ ksum) {
    int chunk = blockIdx.x;
    int bh = blockIdx.y; int b = bh >> 3, h = bh & 7;
    const bf16* qb = qbf + ((size_t)b * NC + h * 32) * NPIX;
    const bf16* kb = kraw + ((size_t)b * NC + h * 32) * NPIX;
    __shared__ __align__(16) short Qs[32][192];
    __shared__ __align__(16) short Ks[32][192];
    __shared__ __align__(16) short Vr[32][3][200];
    __shared__ float ksh[32];
    int t = threadIdx.x;
    int wv = t >> 6, l = t & 63;
    int mh = wv >> 1, eh = wv & 1;
    int cOwn = t >> 3, sOwn = t & 7;
    float w9[9];
#pragma unroll
    for (int i = 0; i < 9; ++i) w9[i] = dwW[(h * 32 + cOwn) * 9 + i];
    if (t < 32) ksh[t] = 0.f;
    f32x4 acc = {0.f, 0.f, 0.f, 0.f};
    float k2s = 0.f;
    for (int rr = 0; rr < 8; ++rr) {
        int row = chunk * 8 + rr;
        __syncthreads();
        for (int e = t; e < 4800; e += 256) {
            int c = e / 150; int r2 = e % 150; int dy = r2 / 50; int j = r2 % 50;
            int gr = row + dy - 1; int gc0 = -4 + 4 * j;
            ushort4 u = make_ushort4(0, 0, 0, 0);
            if (gr >= 0 && gr < NH && gc0 >= 0 && gc0 + 3 < NW)
                u = *reinterpret_cast<const ushort4*>(kb + (size_t)c * NPIX + gr * NW + gc0);
            *reinterpret_cast<ushort4*>(&Vr[c][dy][4 * j]) = u;
        }
        for (int e = t; e < 1536; e += 256) {
            int c = e / 48; int j = e % 48;
            *reinterpret_cast<ushort4*>(&Qs[c][4 * j]) =
                *reinterpret_cast<const ushort4*>(qb + (size_t)c * NPIX + row * NW + 4 * j);
        }
        __syncthreads();
#pragma unroll
        for (int i = 0; i < 24; ++i) {
            int w = sOwn + 8 * i;
            float a = 0.f;
#pragma unroll
            for (int dy = 0; dy < 3; ++dy)
#pragma unroll
                for (int dx = 0; dx < 3; ++dx)
                    a = fmaf(__bfloat162float(*reinterpret_cast<const bf16*>(&Vr[cOwn][dy][w + dx + 3])),
                             w9[dy * 3 + dx], a);
            Ks[cOwn][w] = (short)bfbits(a);
            k2s = fmaf(a, a, k2s);
        }
        __syncthreads();
#pragma unroll
        for (int kk = 0; kk < 6; ++kk) {
            short8v av = *(const short8v*)(&Qs[mh * 16 + (l & 15)][kk * 32 + (l >> 4) * 8]);
            short8v bv = *(const short8v*)(&Ks[eh * 16 + (l & 15)][kk * 32 + (l >> 4) * 8]);
            acc = __builtin_amdgcn_mfma_f32_16x16x32_bf16(av, bv, acc, 0, 0, 0);
        }
    }
    atomicAdd(&ksh[cOwn], k2s);
    __syncthreads();
    if (t < 32) atomicAdd(&ksum[b * NC + h * 32 + t], ksh[t]);
    float* gp = gpart + ((size_t)bh * 24 + chunk) * 1024;
#pragma unroll
    for (int r = 0; r < 4; ++r) {
        int d = mh * 16 + (l >> 4) * 4 + r;
        int e = eh * 16 + (l & 15);
        gp[d * 32 + e] = acc[r];
    }
}

// reduce partials + normalize + temperature + row softmax
__global__ __launch_bounds__(1024) void k_attn(const float* __restrict__ gpart, const float* __restrict__ qsum,
                                               const float* __restrict__ ksum, const float* __restrict__ temp,
                                               float* __restrict__ attn) {
    int bh = blockIdx.x;
    int b = bh >> 3, h = bh & 7;
    int t = threadIdx.x;
    int d = t >> 5, e = t & 31;
    float s = 0.f;
    for (int i = 0; i < 24; ++i) s += gpart[((size_t)bh * 24 + i) * 1024 + t];
    float rq = 1.f / fmaxf(sqrtf(qsum[b * NC + h * 32 + d]), 1e-12f);
    float rk = 1.f / fmaxf(sqrtf(ksum[b * NC + h * 32 + e]), 1e-12f);
    s *= rq * rk * temp[h];
    float m = s;
#pragma unroll
    for (int off = 16; off; off >>= 1) m = fmaxf(m, __shfl_xor(m, off, 32));
    float ex = expf(s - m);
    float sum = ex;
#pragma unroll
    for (int off = 16; off; off >>= 1) sum += __shfl_xor(sum, off, 32);
    attn[(size_t)bh * 1024 + t] = ex / sum;
}

// fold proj into attn -> bf16
__global__ __launch_bounds__(256) void k_wfold(const float* __restrict__ proj, const float* __restrict__ attn,
                                               bf16* __restrict__ wfbf) {
    int o = blockIdx.x, b = blockIdx.y;
    int t = threadIdx.x;
    int h = t >> 5, e = t & 31;
    const float* ap = attn + (size_t)(b * 8 + h) * 1024 + e;
    const float* pp = proj + o * NC + h * 32;
    float acc = 0.f;
#pragma unroll
    for (int d = 0; d < 32; ++d) acc = fmaf(pp[d], ap[d * 32], acc);
    wfbf[((size_t)b * NC + o) * NC + t] = __float2bfloat16(acc);
}

// ---------------- final: out[b,o,seg] = sum_e wf[o,e] * dw(vraw)[e,seg] ----------------
__global__ __launch_bounds__(256) void k_out_dw(const bf16* __restrict__ vraw, const bf16* __restrict__ wfbf,
                                                const float* __restrict__ dwW,
                                                float* __restrict__ out) {
    int sid = blockIdx.x;            // 576 = 192 rows x 3 segs
    int b = blockIdx.y;
    int row = sid / 3, seg = sid % 3, w0 = seg * 64;
    __shared__ __align__(16) short As[256 * 64];
    __shared__ __align__(16) short Bs[64 * 64];
    __shared__ __align__(16) short Vr[64][3][72];
    const bf16* vb = vraw + (size_t)b * NC * NPIX;
    const bf16* wb = wfbf + (size_t)b * NC * NC;
    int t = threadIdx.x;
    int wv = t >> 6, l = t & 63;
    int cOwn = t & 63;
    f32x4 z4 = {0.f, 0.f, 0.f, 0.f};
    f32x4 acc[4][4];
#pragma unroll
    for (int m = 0; m < 4; ++m)
#pragma unroll
        for (int nf = 0; nf < 4; ++nf) acc[m][nf] = z4;
    for (int kc = 0; kc < 256; kc += 64) {
        float w9[9];
#pragma unroll
        for (int i = 0; i < 9; ++i) w9[i] = dwW[(kc + cOwn) * 9 + i];
        __syncthreads();
        for (int e = t; e < 3456; e += 256) {
            int c = e / 54; int r2 = e % 54; int dy = r2 / 18; int j = r2 % 18;
            int gr = row + dy - 1; int gc0 = w0 - 4 + 4 * j;
            ushort4 u = make_ushort4(0, 0, 0, 0);
            if (gr >= 0 && gr < NH && gc0 >= 0 && gc0 + 3 < NW)
                u = *reinterpret_cast<const ushort4*>(vb + (size_t)(kc + c) * NPIX + gr * NW + gc0);
            *reinterpret_cast<ushort4*>(&Vr[c][dy][4 * j]) = u;
        }
#pragma unroll
        for (int i = 0; i < 8; ++i) {
            int blk = t + 256 * i;
            int r = blk >> 3, cb = blk & 7;
            *(short8v*)(As + blk * 8) = *(const short8v*)(wb + (size_t)r * NC + kc + cb * 8);
        }
        __syncthreads();
#pragma unroll
        for (int i = 0; i < 16; ++i) {
            int n = (t >> 6) + 4 * i;
            float a = 0.f;
#pragma unroll
            for (int dy = 0; dy < 3; ++dy)
#pragma unroll
                for (int dx = 0; dx < 3; ++dx)
                    a = fmaf(__bfloat162float(*reinterpret_cast<const bf16*>(&Vr[cOwn][dy][n + dx + 3])),
                             w9[dy * 3 + dx], a);
            Bs[n * 64 + cOwn] = (short)bfbits(a);
        }
        __syncthreads();
#pragma unroll
        for (int kk = 0; kk < 2; ++kk) {
            short8v bfr[4];
#pragma unroll
            for (int nf = 0; nf < 4; ++nf)
                bfr[nf] = *(const short8v*)(Bs + (nf * 16 + (l & 15)) * 64 + kk * 32 + (l >> 4) * 8);
#pragma unroll
            for (int m = 0; m < 4; ++m) {
                short8v av = *(const short8v*)(As + (wv * 64 + m * 16 + (l & 15)) * 64 + kk * 32 + (l >> 4) * 8);
#pragma unroll
                for (int nf = 0; nf < 4; ++nf)
                    acc[m][nf] = __builtin_amdgcn_mfma_f32_16x16x32_bf16(av, bfr[nf], acc[m][nf], 0, 0, 0);
            }
        }
    }
    float* ob = out + (size_t)b * NC * NPIX + (size_t)row * NW + w0;
#pragma unroll
    for (int m = 0; m < 4; ++m)
#pragma unroll
        for (int nf = 0; nf < 4; ++nf)
#pragma unroll
            for (int r = 0; r < 4; ++r) {
                int oo = wv * 64 + m * 16 + (l >> 4) * 4 + r;
                int nn = nf * 16 + (l & 15);
                ob[(size_t)oo * NPIX + nn] = acc[m][nf][r];
            }
}

// ---------------- launcher ----------------

extern "C" void kernel_launch(void* const* d_in, const int* in_sizes, int n_in,
                              void* d_out, int out_size, void* d_ws, size_t ws_size,
                              hipStream_t stream) {
    (void)in_sizes; (void)n_in; (void)out_size;
    const float* x      = (const float*)d_in[0];
    const float* qkv_w  = (const float*)d_in[1];
    const float* qkv_cw = (const float*)d_in[2];
    const float* w5     = (const float*)d_in[3];
    const float* w7     = (const float*)d_in[4];
    const float* w9     = (const float*)d_in[5];
    const float* projw  = (const float*)d_in[6];
    const float* temp   = (const float*)d_in[7];

    // WS: [0:78.7M] sub -> (dead after synth2) -> kraw -> (dead) -> vraw
    //     [78.7M:] smalls (wbf, qsum, ksum, gpart, attn, wfbf)
    const size_t OFF_SM    = 78675968;
    const size_t OFF_WBF   = OFF_SM;                    // 262,144
    const size_t OFF_QSUM  = OFF_SM + 262144;           // 4,096
    const size_t OFF_KSUM  = OFF_QSUM + 4096;           // 4,096
    const size_t OFF_GPART = OFF_KSUM + 4096;           // 3,145,728
    const size_t OFF_ATTN  = OFF_GPART + 3145728;       // 131,072
    const size_t OFF_WF    = OFF_ATTN + 131072;         // 524,288
    const size_t WS_NEED   = OFF_WF + 524288;           // 82,747,392
    if (ws_size < WS_NEED) return;

    char* ws = (char*)d_ws;
    bf16*  sub   = (bf16*)ws;
    bf16*  kraw  = (bf16*)ws;
    bf16*  vraw  = (bf16*)ws;
    bf16*  wbf   = (bf16*)(ws + OFF_WBF);
    float* qsum  = (float*)(ws + OFF_QSUM);
    float* ksum  = (float*)(ws + OFF_KSUM);
    float* gpart = (float*)(ws + OFF_GPART);
    float* attn  = (float*)(ws + OFF_ATTN);
    bf16*  wfbf  = (bf16*)(ws + OFF_WF);

    // OUT: xbf [0:75.5M] + qbf [75.5M:151M] -> final out (overwrites both, dead)
    bf16*  xbf  = (bf16*)d_out;
    bf16*  qbf  = (bf16*)((char*)d_out + 75497472);
    float* out  = (float*)d_out;

    hipMemsetAsync(ws + OFF_QSUM, 0, 8192, stream);   // qsum + ksum

    // wavelet query path: x -> sub -> (dw3x3 + synthesis fused) -> qbf + qsum
    k_dwt<<<dim3(7, NB * NC), 256, 0, stream>>>(x, sub);
    k_synth2<<<dim3(3, 6, NB * NC), 256, 0, stream>>>(sub, w5, w7, w9, qbf, qsum);

    // shared GEMM inputs
    k_xpose<<<dim3(576, 4, NB), 256, 0, stream>>>(x, xbf);
    k_cvtw<<<512, 256, 0, stream>>>(qkv_w, wbf);

    // k path (kraw overwrites dead sub)
    k_gemm_bf<<<dim3(288, 2, NB), 256, 0, stream>>>(xbf, wbf, kraw);
    k_gram_dw<<<dim3(24, 32), 256, 0, stream>>>(qbf, kraw, qkv_cw, gpart, ksum);

    k_attn<<<32, 1024, 0, stream>>>(gpart, qsum, ksum, temp, attn);
    k_wfold<<<dim3(256, NB), 256, 0, stream>>>(projw, attn, wfbf);

    // v path
    k_gemm_bf<<<dim3(288, 2, NB), 256, 0, stream>>>(xbf, wbf + 256 * 256, vraw);
    k_out_dw<<<dim3(576, NB), 256, 0, stream>>>(vraw, wfbf, qkv_cw + 256 * 9, out);
}

// Round 6
// 723.711 us; speedup vs baseline: 1.4311x; 1.1875x over previous
//
#include <hip/hip_runtime.h>
#include <hip/hip_bf16.h>

typedef __hip_bfloat16 bf16;
typedef __attribute__((ext_vector_type(8))) short short8v;   // 8 bf16 = 4 VGPR (MFMA A/B frag)
typedef __attribute__((ext_vector_type(4))) float f32x4;     // MFMA C/D frag

// Problem dims
#define NB 4
#define NC 256
#define NPIX 36864          // 192*192
#define NH 192
#define NW 192
#define SW 98               // db3 subband: (192+8-6)/2+1
#define SH 98
#define SUBN 9604           // SH*SW
#define PSUB 9834496        // NB*NC*SUBN
#define GCH 24              // gram row-chunks (8 rows each)

// db3: analysis correlation kernels (pre-flipped dec filters); synthesis G0S=DEC_LO, G1S=DEC_HI
__device__ __constant__ float cH0A[6] = {  0.33267055295095688f,  0.80689150931333875f,  0.45987750211933132f, -0.13501102001039084f, -0.085441273882241486f, 0.035226291882100656f };
__device__ __constant__ float cH1A[6] = {  0.035226291882100656f, 0.085441273882241486f, -0.13501102001039084f, -0.45987750211933132f,  0.80689150931333875f, -0.33267055295095688f };
__device__ __constant__ float cG0S[6] = {  0.035226291882100656f, -0.085441273882241486f, -0.13501102001039084f, 0.45987750211933132f,  0.80689150931333875f,  0.33267055295095688f };
__device__ __constant__ float cG1S[6] = { -0.33267055295095688f,  0.80689150931333875f, -0.45987750211933132f, -0.13501102001039084f,  0.085441273882241486f, 0.035226291882100656f };

__device__ inline unsigned short bfbits(float f) {
    bf16 h = __float2bfloat16(f);
    return *reinterpret_cast<unsigned short*>(&h);
}
__device__ inline float b2f(short s) {
    return __bfloat162float(*reinterpret_cast<const bf16*>(&s));
}

// ---------------- fused analysis: row DWT + col DWT, vectorized, pow2 indexing ----------------
// grid (7 bands of 14 sub-rows, NB*NC). lo/hi stay in LDS.
__global__ __launch_bounds__(256) void k_dwt(const float* __restrict__ x, bf16* __restrict__ sub) {
    int band = blockIdx.x;
    int bc = blockIdx.y;
    int ho0 = band * 14;
    int jbase = 2 * ho0 - 4;
    __shared__ float s_x[32][192];
    __shared__ float s_lo[32][100];
    __shared__ float s_hi[32][100];
    const float* xp = x + (size_t)bc * NPIX;
    int t = threadIdx.x;
    // load 32 image rows as float4 (zero-fill OOB rows)
#pragma unroll
    for (int i = 0; i < 8; ++i) {
        int e = t + 256 * i;
        int row = e >> 6, c4 = e & 63;
        if (c4 < 48) {
            int jg = jbase + row;
            float4 v = make_float4(0.f, 0.f, 0.f, 0.f);
            if (jg >= 0 && jg < NH) v = *reinterpret_cast<const float4*>(xp + (size_t)jg * NW + c4 * 4);
            *reinterpret_cast<float4*>(&s_x[row][c4 * 4]) = v;
        }
    }
    __syncthreads();
    // row DWT -> s_lo/s_hi : 32 rows x 98
#pragma unroll
    for (int i = 0; i < 16; ++i) {
        int e = t + 256 * i;
        int r = e >> 7, wo = e & 127;
        if (wo < 98) {
            int basec = 2 * wo - 4;
            float la = 0.f, ha = 0.f;
#pragma unroll
            for (int tp = 0; tp < 6; ++tp) {
                int j = basec + tp;
                if (j >= 0 && j < NW) {
                    float v = s_x[r][j];
                    la = fmaf(v, cH0A[tp], la);
                    ha = fmaf(v, cH1A[tp], ha);
                }
            }
            s_lo[r][wo] = la; s_hi[r][wo] = ha;
        }
    }
    __syncthreads();
    // col DWT: 14 x 98 -> 4 planes
    bf16* sp = sub + (size_t)bc * SUBN;
#pragma unroll
    for (int i = 0; i < 7; ++i) {
        int e = t + 256 * i;
        int ho = e >> 7, wo = e & 127;
        if (wo < 98) {
            float ll = 0.f, lh = 0.f, hl = 0.f, hh = 0.f;
#pragma unroll
            for (int tp = 0; tp < 6; ++tp) {
                float lv = s_lo[2 * ho + tp][wo];
                float hv = s_hi[2 * ho + tp][wo];
                ll = fmaf(lv, cH0A[tp], ll); lh = fmaf(lv, cH1A[tp], lh);
                hl = fmaf(hv, cH0A[tp], hl); hh = fmaf(hv, cH1A[tp], hh);
            }
            size_t o = (size_t)(ho0 + ho) * SW + wo;
            sp[o] = __float2bfloat16(ll);
            sp[(size_t)PSUB + o] = __float2bfloat16(lh);
            sp[2 * (size_t)PSUB + o] = __float2bfloat16(hl);
            sp[3 * (size_t)PSUB + o] = __float2bfloat16(hh);
        }
    }
}

// ---------------- fused: dw3x3(subbands) + col-synth + row-synth -> qbf + qsum ----------------
__global__ __launch_bounds__(256) void k_synth2(const bf16* __restrict__ sub,
                                                const float* __restrict__ w5, const float* __restrict__ w7,
                                                const float* __restrict__ w9,
                                                bf16* __restrict__ q, float* __restrict__ qsum) {
    int w0 = blockIdx.x * 64, h0 = blockIdx.y * 32;
    int bc = blockIdx.z;
    int c = bc & 255;
    int jh0 = h0 >> 1, jw0 = w0 >> 1;
    __shared__ short s_sub[4][20][38];
    __shared__ float s_c[4][18][34];
    __shared__ float s_lh[2][32][34];
    __shared__ float s_w[4][9];
    __shared__ float red[4];
    const bf16* sp = sub + (size_t)bc * SUBN;
    int t = threadIdx.x;
    if (t < 36) {
        int f = t / 9, k = t - f * 9;
        const float* wsel = (f <= 1) ? w5 : (f == 2 ? w7 : w9);
        s_w[f][k] = wsel[c * 9 + k];
    }
    for (int e = t; e < 1520; e += 256) {
        int pl = e / 380;
        int r2 = e - pl * 380;
        int r = r2 / 19, j = r2 - r * 19;
        int gr = jh0 - 1 + r;
        int gc = jw0 - 2 + 2 * j;
        ushort2 u = make_ushort2(0, 0);
        if (gr >= 0 && gr < SH && gc >= 0 && gc < 97)
            u = *reinterpret_cast<const ushort2*>(sp + (size_t)pl * PSUB + (size_t)gr * SW + gc);
        *reinterpret_cast<ushort2*>(&s_sub[pl][r][2 * j]) = u;
    }
    float ge0[3] = { cG0S[1], cG0S[3], cG0S[5] };
    float go0[3] = { cG0S[0], cG0S[2], cG0S[4] };
    float ge1[3] = { cG1S[1], cG1S[3], cG1S[5] };
    float go1[3] = { cG1S[0], cG1S[2], cG1S[4] };
    __syncthreads();
    for (int e = t; e < 2448; e += 256) {
        int pl = e / 612;
        int r2 = e - pl * 612;
        int r = r2 / 34, cc = r2 - r * 34;
        const float* wp = s_w[pl];
        float a = 0.f;
#pragma unroll
        for (int ky = 0; ky < 3; ++ky)
#pragma unroll
            for (int kx = 0; kx < 3; ++kx)
                a = fmaf(b2f(s_sub[pl][r + ky][cc + 1 + kx]), wp[ky * 3 + kx], a);
        s_c[pl][r][cc] = a;
    }
    __syncthreads();
    for (int e = t; e < 2176; e += 256) {
        int which = e / 1088;
        int r2 = e - which * 1088;
        int hh = r2 / 34, cc = r2 - hh * 34;
        int par = hh & 1;
        int j0 = hh >> 1;
        float a = 0.f;
#pragma unroll
        for (int i = 0; i < 3; ++i) {
            float g0 = par ? go0[i] : ge0[i];
            float g1 = par ? go1[i] : ge1[i];
            a = fmaf(s_c[2 * which][j0 + i][cc], g0, a);
            a = fmaf(s_c[2 * which + 1][j0 + i][cc], g1, a);
        }
        s_lh[which][hh][cc] = a;
    }
    __syncthreads();
    float lsum = 0.f;
    bf16* qp = q + (size_t)bc * NPIX;
#pragma unroll
    for (int it = 0; it < 8; ++it) {
        int e = t + 256 * it;
        int hh = e >> 6, ww = e & 63;
        int par = ww & 1;
        int j0 = ww >> 1;
        float a = 0.f;
#pragma unroll
        for (int i = 0; i < 3; ++i) {
            float g0 = par ? go0[i] : ge0[i];
            float g1 = par ? go1[i] : ge1[i];
            a = fmaf(s_lh[0][hh][j0 + i], g0, a);
            a = fmaf(s_lh[1][hh][j0 + i], g1, a);
        }
        qp[(size_t)(h0 + hh) * NW + w0 + ww] = __float2bfloat16(a);
        lsum = fmaf(a, a, lsum);
    }
#pragma unroll
    for (int off = 32; off; off >>= 1) lsum += __shfl_down(lsum, off, 64);
    if ((t & 63) == 0) red[t >> 6] = lsum;
    __syncthreads();
    if (t == 0) atomicAdd(&qsum[bc], red[0] + red[1] + red[2] + red[3]);
}

// ---------------- transpose-convert: x [b][c][n] f32 -> xT [b][n][c] bf16 ----------------

__global__ __launch_bounds__(256) void k_xpose(const float* __restrict__ x, bf16* __restrict__ xT) {
    __shared__ float T[64][68];
    int nt = blockIdx.x, ct = blockIdx.y, b = blockIdx.z;
    int n0 = nt * 64, c0 = ct * 64;
    const float* xb = x + ((size_t)b * NC + c0) * NPIX + n0;
    int t = threadIdx.x;
    int tr = t >> 4, tc4 = (t & 15) * 4;
#pragma unroll
    for (int i = 0; i < 4; ++i) {
        int cc = tr + i * 16;
        float4 v = *reinterpret_cast<const float4*>(xb + (size_t)cc * NPIX + tc4);
        T[cc][tc4] = v.x; T[cc][tc4 + 1] = v.y; T[cc][tc4 + 2] = v.z; T[cc][tc4 + 3] = v.w;
    }
    __syncthreads();
    bf16* ob = xT + ((size_t)b * NPIX + n0) * NC + c0;
#pragma unroll
    for (int i = 0; i < 4; ++i) {
        int nn = tr + i * 16;
        ushort4 u;
        u.x = bfbits(T[tc4][nn]); u.y = bfbits(T[tc4 + 1][nn]);
        u.z = bfbits(T[tc4 + 2][nn]); u.w = bfbits(T[tc4 + 3][nn]);
        *reinterpret_cast<ushort4*>(ob + (size_t)nn * NC + tc4) = u;
    }
}

// convert qkv_w (512x256 f32) -> bf16
__global__ __launch_bounds__(256) void k_cvtw(const float* __restrict__ w, bf16* __restrict__ wb) {
    int idx = blockIdx.x * 256 + threadIdx.x;
    if (idx < 512 * 256) wb[idx] = __float2bfloat16(w[idx]);
}

// ---------------- MFMA GEMM: Out[b,o,n] = sum_c W[o,c] * xT[b,n,c]  (128x128 tile) ----------------
__global__ __launch_bounds__(256) void k_gemm_bf(const bf16* __restrict__ xT, const bf16* __restrict__ wbf,
                                                 bf16* __restrict__ outp) {
    __shared__ __align__(16) short As[128 * 64];
    __shared__ __align__(16) short Bs[128 * 64];
    int nt = blockIdx.x, ot = blockIdx.y, b = blockIdx.z;
    int n0 = nt * 128, o0 = ot * 128;
    const bf16* xb = xT + (size_t)b * NPIX * NC;
    int t = threadIdx.x;
    int wv = t >> 6, l = t & 63;
    int wr = wv >> 1, wc = wv & 1;
    f32x4 z4 = {0.f, 0.f, 0.f, 0.f};
    f32x4 acc[4][4];
#pragma unroll
    for (int m = 0; m < 4; ++m)
#pragma unroll
        for (int nf = 0; nf < 4; ++nf) acc[m][nf] = z4;
    for (int kc = 0; kc < 256; kc += 64) {
        __syncthreads();
#pragma unroll
        for (int i = 0; i < 4; ++i) {
            int blk = t + 256 * i;
            int r = blk >> 3, cb = blk & 7;
            *(short8v*)(As + blk * 8) = *(const short8v*)(wbf + (size_t)(o0 + r) * NC + kc + cb * 8);
            *(short8v*)(Bs + blk * 8) = *(const short8v*)(xb + (size_t)(n0 + r) * NC + kc + cb * 8);
        }
        __syncthreads();
#pragma unroll
        for (int kk = 0; kk < 2; ++kk) {
            short8v av[4], bv[4];
#pragma unroll
            for (int m = 0; m < 4; ++m)
                av[m] = *(const short8v*)(As + (wr * 64 + m * 16 + (l & 15)) * 64 + kk * 32 + (l >> 4) * 8);
#pragma unroll
            for (int nf = 0; nf < 4; ++nf)
                bv[nf] = *(const short8v*)(Bs + (wc * 64 + nf * 16 + (l & 15)) * 64 + kk * 32 + (l >> 4) * 8);
#pragma unroll
            for (int m = 0; m < 4; ++m)
#pragma unroll
                for (int nf = 0; nf < 4; ++nf)
                    acc[m][nf] = __builtin_amdgcn_mfma_f32_16x16x32_bf16(av[m], bv[nf], acc[m][nf], 0, 0, 0);
        }
    }
    bf16* ob = outp + (size_t)b * NC * NPIX;
#pragma unroll
    for (int m = 0; m < 4; ++m)
#pragma unroll
        for (int nf = 0; nf < 4; ++nf)
#pragma unroll
            for (int r = 0; r < 4; ++r) {
                int oo = o0 + wr * 64 + m * 16 + (l >> 4) * 4 + r;
                int nn = n0 + wc * 64 + nf * 16 + (l & 15);
                ob[(size_t)oo * NPIX + nn] = __float2bfloat16(acc[m][nf][r]);
            }
}

// ---------------- Gram + fused dw3x3, register-direct (no staging) ----------------
// grid (GCH=24 chunks of 8 rows, 32 bh). 4 waves; wave wv owns rows chunk*8+wv*2 .. +2.
// Per 32-pixel step: lane l loads A-frags (q ch l&15, l&15+16) and COMPUTES B-frags
// (dw3x3 of kraw ch l&15, l&15+16) in registers; 4 quadrant MFMAs. ksum folded.
__device__ inline short8v dw8(const bf16* __restrict__ chan, int r, int cb,
                              const float* __restrict__ w, float& ks) {
    float v[3][10];
#pragma unroll
    for (int ri = 0; ri < 3; ++ri) {
        int r2 = r + ri - 1;
        if (r2 < 0 || r2 >= NH) {
#pragma unroll
            for (int j = 0; j < 10; ++j) v[ri][j] = 0.f;
        } else {
            const bf16* p = chan + (size_t)r2 * NW + cb;
            short8v m = *(const short8v*)p;
            v[ri][0] = (cb > 0) ? __bfloat162float(p[-1]) : 0.f;
#pragma unroll
            for (int j = 0; j < 8; ++j) v[ri][j + 1] = b2f(m[j]);
            v[ri][9] = (cb < 184) ? __bfloat162float(p[8]) : 0.f;
        }
    }
    short8v out;
#pragma unroll
    for (int j = 0; j < 8; ++j) {
        float a = 0.f;
#pragma unroll
        for (int ri = 0; ri < 3; ++ri) {
            a = fmaf(v[ri][j],     w[ri * 3 + 0], a);
            a = fmaf(v[ri][j + 1], w[ri * 3 + 1], a);
            a = fmaf(v[ri][j + 2], w[ri * 3 + 2], a);
        }
        ks = fmaf(a, a, ks);
        out[j] = (short)bfbits(a);
    }
    return out;
}

__global__ __launch_bounds__(256) void k_gram_dw(const bf16* __restrict__ qbf, const bf16* __restrict__ kraw,
                                                 const float* __restrict__ dwW,
                                                 float* __restrict__ gpart, float* __restrict__ ksum) {
    int chunk = blockIdx.x;
    int bh = blockIdx.y; int b = bh >> 3, h = bh & 7;
    const bf16* qb = qbf + ((size_t)b * NC + h * 32) * NPIX;
    const bf16* kb = kraw + ((size_t)b * NC + h * 32) * NPIX;
    __shared__ float sg[4][1024];
    __shared__ float ksh[32];
    int t = threadIdx.x;
    int wv = t >> 6, l = t & 63;
    int dlo = l & 15, kslot = l >> 4;
    float wA[9], wB[9];
#pragma unroll
    for (int i = 0; i < 9; ++i) {
        wA[i] = dwW[(h * 32 + dlo) * 9 + i];
        wB[i] = dwW[(h * 32 + dlo + 16) * 9 + i];
    }
    const bf16* q0 = qb + (size_t)dlo * NPIX;
    const bf16* q1 = qb + (size_t)(dlo + 16) * NPIX;
    const bf16* k0 = kb + (size_t)dlo * NPIX;
    const bf16* k1 = kb + (size_t)(dlo + 16) * NPIX;
    f32x4 z4 = {0.f, 0.f, 0.f, 0.f};
    f32x4 a00 = z4, a01 = z4, a10 = z4, a11 = z4;
    float ks0 = 0.f, ks1 = 0.f;
    int r0 = chunk * 8 + wv * 2;
#pragma unroll
    for (int rr = 0; rr < 2; ++rr) {
        int r = r0 + rr;
#pragma unroll
        for (int c0 = 0; c0 < 192; c0 += 32) {
            int cb = c0 + kslot * 8;
            short8v av0 = *(const short8v*)(q0 + (size_t)r * NW + cb);
            short8v av1 = *(const short8v*)(q1 + (size_t)r * NW + cb);
            short8v bv0 = dw8(k0, r, cb, wA, ks0);
            short8v bv1 = dw8(k1, r, cb, wB, ks1);
            a00 = __builtin_amdgcn_mfma_f32_16x16x32_bf16(av0, bv0, a00, 0, 0, 0);
            a01 = __builtin_amdgcn_mfma_f32_16x16x32_bf16(av0, bv1, a01, 0, 0, 0);
            a10 = __builtin_amdgcn_mfma_f32_16x16x32_bf16(av1, bv0, a10, 0, 0, 0);
            a11 = __builtin_amdgcn_mfma_f32_16x16x32_bf16(av1, bv1, a11, 0, 0, 0);
        }
    }
    if (t < 32) ksh[t] = 0.f;
    // write quadrants to LDS: d = dh*16 + kslot*4 + j, e = eh*16 + dlo
#pragma unroll
    for (int j = 0; j < 4; ++j) {
        int dA = kslot * 4 + j, dB = 16 + kslot * 4 + j;
        sg[wv][dA * 32 + dlo]      = a00[j];
        sg[wv][dA * 32 + 16 + dlo] = a01[j];
        sg[wv][dB * 32 + dlo]      = a10[j];
        sg[wv][dB * 32 + 16 + dlo] = a11[j];
    }
    __syncthreads();
    float* gp = gpart + ((size_t)bh * GCH + chunk) * 1024;
#pragma unroll
    for (int i = 0; i < 4; ++i) {
        int e = t + 256 * i;
        gp[e] = sg[0][e] + sg[1][e] + sg[2][e] + sg[3][e];
    }
    atomicAdd(&ksh[dlo], ks0);
    atomicAdd(&ksh[dlo + 16], ks1);
    __syncthreads();
    if (t < 32) atomicAdd(&ksum[b * NC + h * 32 + t], ksh[t]);
}

// reduce partials + normalize + temperature + row softmax
__global__ __launch_bounds__(1024) void k_attn(const float* __restrict__ gpart, const float* __restrict__ qsum,
                                               const float* __restrict__ ksum, const float* __restrict__ temp,
                                               float* __restrict__ attn) {
    int bh = blockIdx.x;
    int b = bh >> 3, h = bh & 7;
    int t = threadIdx.x;
    int d = t >> 5, e = t & 31;
    float s = 0.f;
    for (int i = 0; i < GCH; ++i) s += gpart[((size_t)bh * GCH + i) * 1024 + t];
    float rq = 1.f / fmaxf(sqrtf(qsum[b * NC + h * 32 + d]), 1e-12f);
    float rk = 1.f / fmaxf(sqrtf(ksum[b * NC + h * 32 + e]), 1e-12f);
    s *= rq * rk * temp[h];
    float m = s;
#pragma unroll
    for (int off = 16; off; off >>= 1) m = fmaxf(m, __shfl_xor(m, off, 32));
    float ex = expf(s - m);
    float sum = ex;
#pragma unroll
    for (int off = 16; off; off >>= 1) sum += __shfl_xor(sum, off, 32);
    attn[(size_t)bh * 1024 + t] = ex / sum;
}

// fold proj into attn -> bf16
__global__ __launch_bounds__(256) void k_wfold(const float* __restrict__ proj, const float* __restrict__ attn,
                                               bf16* __restrict__ wfbf) {
    int o = blockIdx.x, b = blockIdx.y;
    int t = threadIdx.x;
    int h = t >> 5, e = t & 31;
    const float* ap = attn + (size_t)(b * 8 + h) * 1024 + e;
    const float* pp = proj + o * NC + h * 32;
    float acc = 0.f;
#pragma unroll
    for (int d = 0; d < 32; ++d) acc = fmaf(pp[d], ap[d * 32], acc);
    wfbf[((size_t)b * NC + o) * NC + t] = __float2bfloat16(acc);
}

// ---------------- final: out[b,o,seg] = sum_e wf[o,e] * dw(vraw)[e,seg] ----------------
__global__ __launch_bounds__(256) void k_out_dw(const bf16* __restrict__ vraw, const bf16* __restrict__ wfbf,
                                                const float* __restrict__ dwW,
                                                float* __restrict__ out) {
    int sid = blockIdx.x;            // 576 = 192 rows x 3 segs
    int b = blockIdx.y;
    int row = sid / 3, seg = sid % 3, w0 = seg * 64;
    __shared__ __align__(16) short As[256 * 64];
    __shared__ __align__(16) short Bs[64 * 64];
    __shared__ __align__(16) short Vr[64][3][72];
    const bf16* vb = vraw + (size_t)b * NC * NPIX;
    const bf16* wb = wfbf + (size_t)b * NC * NC;
    int t = threadIdx.x;
    int wv = t >> 6, l = t & 63;
    int cOwn = t & 63;
    f32x4 z4 = {0.f, 0.f, 0.f, 0.f};
    f32x4 acc[4][4];
#pragma unroll
    for (int m = 0; m < 4; ++m)
#pragma unroll
        for (int nf = 0; nf < 4; ++nf) acc[m][nf] = z4;
    for (int kc = 0; kc < 256; kc += 64) {
        float w9[9];
#pragma unroll
        for (int i = 0; i < 9; ++i) w9[i] = dwW[(kc + cOwn) * 9 + i];
        __syncthreads();
        for (int e = t; e < 3456; e += 256) {
            int c = e / 54; int r2 = e % 54; int dy = r2 / 18; int j = r2 % 18;
            int gr = row + dy - 1; int gc0 = w0 - 4 + 4 * j;
            ushort4 u = make_ushort4(0, 0, 0, 0);
            if (gr >= 0 && gr < NH && gc0 >= 0 && gc0 + 3 < NW)
                u = *reinterpret_cast<const ushort4*>(vb + (size_t)(kc + c) * NPIX + gr * NW + gc0);
            *reinterpret_cast<ushort4*>(&Vr[c][dy][4 * j]) = u;
        }
#pragma unroll
        for (int i = 0; i < 8; ++i) {
            int blk = t + 256 * i;
            int r = blk >> 3, cb = blk & 7;
            *(short8v*)(As + blk * 8) = *(const short8v*)(wb + (size_t)r * NC + kc + cb * 8);
        }
        __syncthreads();
#pragma unroll
        for (int i = 0; i < 16; ++i) {
            int n = (t >> 6) + 4 * i;
            float a = 0.f;
#pragma unroll
            for (int dy = 0; dy < 3; ++dy)
#pragma unroll
                for (int dx = 0; dx < 3; ++dx)
                    a = fmaf(__bfloat162float(*reinterpret_cast<const bf16*>(&Vr[cOwn][dy][n + dx + 3])),
                             w9[dy * 3 + dx], a);
            Bs[n * 64 + cOwn] = (short)bfbits(a);
        }
        __syncthreads();
#pragma unroll
        for (int kk = 0; kk < 2; ++kk) {
            short8v bfr[4];
#pragma unroll
            for (int nf = 0; nf < 4; ++nf)
                bfr[nf] = *(const short8v*)(Bs + (nf * 16 + (l & 15)) * 64 + kk * 32 + (l >> 4) * 8);
#pragma unroll
            for (int m = 0; m < 4; ++m) {
                short8v av = *(const short8v*)(As + (wv * 64 + m * 16 + (l & 15)) * 64 + kk * 32 + (l >> 4) * 8);
#pragma unroll
                for (int nf = 0; nf < 4; ++nf)
                    acc[m][nf] = __builtin_amdgcn_mfma_f32_16x16x32_bf16(av, bfr[nf], acc[m][nf], 0, 0, 0);
            }
        }
    }
    float* ob = out + (size_t)b * NC * NPIX + (size_t)row * NW + w0;
#pragma unroll
    for (int m = 0; m < 4; ++m)
#pragma unroll
        for (int nf = 0; nf < 4; ++nf)
#pragma unroll
            for (int r = 0; r < 4; ++r) {
                int oo = wv * 64 + m * 16 + (l >> 4) * 4 + r;
                int nn = nf * 16 + (l & 15);
                ob[(size_t)oo * NPIX + nn] = acc[m][nf][r];
            }
}

// ---------------- launcher ----------------

extern "C" void kernel_launch(void* const* d_in, const int* in_sizes, int n_in,
                              void* d_out, int out_size, void* d_ws, size_t ws_size,
                              hipStream_t stream) {
    (void)in_sizes; (void)n_in; (void)out_size;
    const float* x      = (const float*)d_in[0];
    const float* qkv_w  = (const float*)d_in[1];
    const float* qkv_cw = (const float*)d_in[2];
    const float* w5     = (const float*)d_in[3];
    const float* w7     = (const float*)d_in[4];
    const float* w9     = (const float*)d_in[5];
    const float* projw  = (const float*)d_in[6];
    const float* temp   = (const float*)d_in[7];

    // WS: [0:78.7M] sub -> (dead after synth2) -> kraw -> (dead) -> vraw
    //     [78.7M:] smalls (wbf, qsum, ksum, gpart, attn, wfbf)
    const size_t OFF_SM    = 78675968;
    const size_t OFF_WBF   = OFF_SM;                    // 262,144
    const size_t OFF_QSUM  = OFF_SM + 262144;           // 4,096
    const size_t OFF_KSUM  = OFF_QSUM + 4096;           // 4,096
    const size_t OFF_GPART = OFF_KSUM + 4096;           // 3,145,728 (GCH=24)
    const size_t OFF_ATTN  = OFF_GPART + 3145728;       // 131,072
    const size_t OFF_WF    = OFF_ATTN + 131072;         // 524,288
    const size_t WS_NEED   = OFF_WF + 524288;           // 82,747,392
    if (ws_size < WS_NEED) return;

    char* ws = (char*)d_ws;
    bf16*  sub   = (bf16*)ws;
    bf16*  kraw  = (bf16*)ws;
    bf16*  vraw  = (bf16*)ws;
    bf16*  wbf   = (bf16*)(ws + OFF_WBF);
    float* qsum  = (float*)(ws + OFF_QSUM);
    float* ksum  = (float*)(ws + OFF_KSUM);
    float* gpart = (float*)(ws + OFF_GPART);
    float* attn  = (float*)(ws + OFF_ATTN);
    bf16*  wfbf  = (bf16*)(ws + OFF_WF);

    // OUT: xbf [0:75.5M] + qbf [75.5M:151M] -> final out (overwrites both, dead)
    bf16*  xbf  = (bf16*)d_out;
    bf16*  qbf  = (bf16*)((char*)d_out + 75497472);
    float* out  = (float*)d_out;

    hipMemsetAsync(ws + OFF_QSUM, 0, 8192, stream);   // qsum + ksum

    // wavelet query path: x -> sub -> (dw3x3 + synthesis fused) -> qbf + qsum
    k_dwt<<<dim3(7, NB * NC), 256, 0, stream>>>(x, sub);
    k_synth2<<<dim3(3, 6, NB * NC), 256, 0, stream>>>(sub, w5, w7, w9, qbf, qsum);

    // shared GEMM inputs
    k_xpose<<<dim3(576, 4, NB), 256, 0, stream>>>(x, xbf);
    k_cvtw<<<512, 256, 0, stream>>>(qkv_w, wbf);

    // k path (kraw overwrites dead sub)
    k_gemm_bf<<<dim3(288, 2, NB), 256, 0, stream>>>(xbf, wbf, kraw);
    k_gram_dw<<<dim3(GCH, 32), 256, 0, stream>>>(qbf, kraw, qkv_cw, gpart, ksum);

    k_attn<<<32, 1024, 0, stream>>>(gpart, qsum, ksum, temp, attn);
    k_wfold<<<dim3(256, NB), 256, 0, stream>>>(projw, attn, wfbf);

    // v path
    k_gemm_bf<<<dim3(288, 2, NB), 256, 0, stream>>>(xbf, wbf + 256 * 256, vraw);
    k_out_dw<<<dim3(576, NB), 256, 0, stream>>>(vraw, wfbf, qkv_cw + 256 * 9, out);
}

// Round 7
// 621.749 us; speedup vs baseline: 1.6657x; 1.1640x over previous
//
#include <hip/hip_runtime.h>
#include <hip/hip_bf16.h>

typedef __hip_bfloat16 bf16;
typedef __attribute__((ext_vector_type(8))) short short8v;   // 8 bf16 = 4 VGPR (MFMA A/B frag)
typedef __attribute__((ext_vector_type(4))) float f32x4;     // MFMA C/D frag

// Problem dims
#define NB 4
#define NC 256
#define NPIX 36864          // 192*192
#define NH 192
#define NW 192
#define SW 98               // db3 subband: (192+8-6)/2+1
#define SH 98
#define SUBN 9604           // SH*SW
#define PSUB 9834496        // NB*NC*SUBN
#define GCH 24              // gram row-chunks (8 rows each)

// db3: analysis correlation kernels (pre-flipped dec filters); synthesis G0S=DEC_LO, G1S=DEC_HI
__device__ __constant__ float cH0A[6] = {  0.33267055295095688f,  0.80689150931333875f,  0.45987750211933132f, -0.13501102001039084f, -0.085441273882241486f, 0.035226291882100656f };
__device__ __constant__ float cH1A[6] = {  0.035226291882100656f, 0.085441273882241486f, -0.13501102001039084f, -0.45987750211933132f,  0.80689150931333875f, -0.33267055295095688f };
__device__ __constant__ float cG0S[6] = {  0.035226291882100656f, -0.085441273882241486f, -0.13501102001039084f, 0.45987750211933132f,  0.80689150931333875f,  0.33267055295095688f };
__device__ __constant__ float cG1S[6] = { -0.33267055295095688f,  0.80689150931333875f, -0.45987750211933132f, -0.13501102001039084f,  0.085441273882241486f, 0.035226291882100656f };

__device__ inline unsigned short bfbits(float f) {
    bf16 h = __float2bfloat16(f);
    return *reinterpret_cast<unsigned short*>(&h);
}
__device__ inline float b2f(short s) {
    return __bfloat162float(*reinterpret_cast<const bf16*>(&s));
}

// ---------------- fused analysis: row DWT + col DWT ----------------
__global__ __launch_bounds__(256) void k_dwt(const float* __restrict__ x, bf16* __restrict__ sub) {
    int band = blockIdx.x;
    int bc = blockIdx.y;
    int ho0 = band * 14;
    int jbase = 2 * ho0 - 4;
    __shared__ float s_x[32][192];
    __shared__ float s_lo[32][100];
    __shared__ float s_hi[32][100];
    const float* xp = x + (size_t)bc * NPIX;
    int t = threadIdx.x;
#pragma unroll
    for (int i = 0; i < 8; ++i) {
        int e = t + 256 * i;
        int row = e >> 6, c4 = e & 63;
        if (c4 < 48) {
            int jg = jbase + row;
            float4 v = make_float4(0.f, 0.f, 0.f, 0.f);
            if (jg >= 0 && jg < NH) v = *reinterpret_cast<const float4*>(xp + (size_t)jg * NW + c4 * 4);
            *reinterpret_cast<float4*>(&s_x[row][c4 * 4]) = v;
        }
    }
    __syncthreads();
#pragma unroll
    for (int i = 0; i < 16; ++i) {
        int e = t + 256 * i;
        int r = e >> 7, wo = e & 127;
        if (wo < 98) {
            int basec = 2 * wo - 4;
            float la = 0.f, ha = 0.f;
#pragma unroll
            for (int tp = 0; tp < 6; ++tp) {
                int j = basec + tp;
                if (j >= 0 && j < NW) {
                    float v = s_x[r][j];
                    la = fmaf(v, cH0A[tp], la);
                    ha = fmaf(v, cH1A[tp], ha);
                }
            }
            s_lo[r][wo] = la; s_hi[r][wo] = ha;
        }
    }
    __syncthreads();
    bf16* sp = sub + (size_t)bc * SUBN;
#pragma unroll
    for (int i = 0; i < 7; ++i) {
        int e = t + 256 * i;
        int ho = e >> 7, wo = e & 127;
        if (wo < 98) {
            float ll = 0.f, lh = 0.f, hl = 0.f, hh = 0.f;
#pragma unroll
            for (int tp = 0; tp < 6; ++tp) {
                float lv = s_lo[2 * ho + tp][wo];
                float hv = s_hi[2 * ho + tp][wo];
                ll = fmaf(lv, cH0A[tp], ll); lh = fmaf(lv, cH1A[tp], lh);
                hl = fmaf(hv, cH0A[tp], hl); hh = fmaf(hv, cH1A[tp], hh);
            }
            size_t o = (size_t)(ho0 + ho) * SW + wo;
            sp[o] = __float2bfloat16(ll);
            sp[(size_t)PSUB + o] = __float2bfloat16(lh);
            sp[2 * (size_t)PSUB + o] = __float2bfloat16(hl);
            sp[3 * (size_t)PSUB + o] = __float2bfloat16(hh);
        }
    }
}

// ---------------- fused: dw3x3(subbands) + col-synth + row-synth -> qbf + qsum ----------------
__global__ __launch_bounds__(256) void k_synth2(const bf16* __restrict__ sub,
                                                const float* __restrict__ w5, const float* __restrict__ w7,
                                                const float* __restrict__ w9,
                                                bf16* __restrict__ q, float* __restrict__ qsum) {
    int w0 = blockIdx.x * 64, h0 = blockIdx.y * 32;
    int bc = blockIdx.z;
    int c = bc & 255;
    int jh0 = h0 >> 1, jw0 = w0 >> 1;
    __shared__ short s_sub[4][20][38];
    __shared__ float s_c[4][18][34];
    __shared__ float s_lh[2][32][34];
    __shared__ float s_w[4][9];
    __shared__ float red[4];
    const bf16* sp = sub + (size_t)bc * SUBN;
    int t = threadIdx.x;
    if (t < 36) {
        int f = t / 9, k = t - f * 9;
        const float* wsel = (f <= 1) ? w5 : (f == 2 ? w7 : w9);
        s_w[f][k] = wsel[c * 9 + k];
    }
    for (int e = t; e < 1520; e += 256) {
        int pl = e / 380;
        int r2 = e - pl * 380;
        int r = r2 / 19, j = r2 - r * 19;
        int gr = jh0 - 1 + r;
        int gc = jw0 - 2 + 2 * j;
        ushort2 u = make_ushort2(0, 0);
        if (gr >= 0 && gr < SH && gc >= 0 && gc < 97)
            u = *reinterpret_cast<const ushort2*>(sp + (size_t)pl * PSUB + (size_t)gr * SW + gc);
        *reinterpret_cast<ushort2*>(&s_sub[pl][r][2 * j]) = u;
    }
    float ge0[3] = { cG0S[1], cG0S[3], cG0S[5] };
    float go0[3] = { cG0S[0], cG0S[2], cG0S[4] };
    float ge1[3] = { cG1S[1], cG1S[3], cG1S[5] };
    float go1[3] = { cG1S[0], cG1S[2], cG1S[4] };
    __syncthreads();
    for (int e = t; e < 2448; e += 256) {
        int pl = e / 612;
        int r2 = e - pl * 612;
        int r = r2 / 34, cc = r2 - r * 34;
        const float* wp = s_w[pl];
        float a = 0.f;
#pragma unroll
        for (int ky = 0; ky < 3; ++ky)
#pragma unroll
            for (int kx = 0; kx < 3; ++kx)
                a = fmaf(b2f(s_sub[pl][r + ky][cc + 1 + kx]), wp[ky * 3 + kx], a);
        s_c[pl][r][cc] = a;
    }
    __syncthreads();
    for (int e = t; e < 2176; e += 256) {
        int which = e / 1088;
        int r2 = e - which * 1088;
        int hh = r2 / 34, cc = r2 - hh * 34;
        int par = hh & 1;
        int j0 = hh >> 1;
        float a = 0.f;
#pragma unroll
        for (int i = 0; i < 3; ++i) {
            float g0 = par ? go0[i] : ge0[i];
            float g1 = par ? go1[i] : ge1[i];
            a = fmaf(s_c[2 * which][j0 + i][cc], g0, a);
            a = fmaf(s_c[2 * which + 1][j0 + i][cc], g1, a);
        }
        s_lh[which][hh][cc] = a;
    }
    __syncthreads();
    float lsum = 0.f;
    bf16* qp = q + (size_t)bc * NPIX;
#pragma unroll
    for (int it = 0; it < 8; ++it) {
        int e = t + 256 * it;
        int hh = e >> 6, ww = e & 63;
        int par = ww & 1;
        int j0 = ww >> 1;
        float a = 0.f;
#pragma unroll
        for (int i = 0; i < 3; ++i) {
            float g0 = par ? go0[i] : ge0[i];
            float g1 = par ? go1[i] : ge1[i];
            a = fmaf(s_lh[0][hh][j0 + i], g0, a);
            a = fmaf(s_lh[1][hh][j0 + i], g1, a);
        }
        qp[(size_t)(h0 + hh) * NW + w0 + ww] = __float2bfloat16(a);
        lsum = fmaf(a, a, lsum);
    }
#pragma unroll
    for (int off = 32; off; off >>= 1) lsum += __shfl_down(lsum, off, 64);
    if ((t & 63) == 0) red[t >> 6] = lsum;
    __syncthreads();
    if (t == 0) atomicAdd(&qsum[bc], red[0] + red[1] + red[2] + red[3]);
}

// ---------------- transpose-convert: x [b][c][n] f32 -> xT [b][n][c] bf16 ----------------
__global__ __launch_bounds__(256) void k_xpose(const float* __restrict__ x, bf16* __restrict__ xT) {
    __shared__ float T[64][68];
    int nt = blockIdx.x, ct = blockIdx.y, b = blockIdx.z;
    int n0 = nt * 64, c0 = ct * 64;
    const float* xb = x + ((size_t)b * NC + c0) * NPIX + n0;
    int t = threadIdx.x;
    int tr = t >> 4, tc4 = (t & 15) * 4;
#pragma unroll
    for (int i = 0; i < 4; ++i) {
        int cc = tr + i * 16;
        float4 v = *reinterpret_cast<const float4*>(xb + (size_t)cc * NPIX + tc4);
        T[cc][tc4] = v.x; T[cc][tc4 + 1] = v.y; T[cc][tc4 + 2] = v.z; T[cc][tc4 + 3] = v.w;
    }
    __syncthreads();
    bf16* ob = xT + ((size_t)b * NPIX + n0) * NC + c0;
#pragma unroll
    for (int i = 0; i < 4; ++i) {
        int nn = tr + i * 16;
        ushort4 u;
        u.x = bfbits(T[tc4][nn]); u.y = bfbits(T[tc4 + 1][nn]);
        u.z = bfbits(T[tc4 + 2][nn]); u.w = bfbits(T[tc4 + 3][nn]);
        *reinterpret_cast<ushort4*>(ob + (size_t)nn * NC + tc4) = u;
    }
}

// convert qkv_w (512x256 f32) -> bf16
__global__ __launch_bounds__(256) void k_cvtw(const float* __restrict__ w, bf16* __restrict__ wb) {
    int idx = blockIdx.x * 256 + threadIdx.x;
    if (idx < 512 * 256) wb[idx] = __float2bfloat16(w[idx]);
}

// ---------------- MFMA GEMM: Out[b,o,n] = sum_k W[(b),o,k] * X[b,n,k]  (128x128 tile) ----------------
// T2 XOR-swizzle on LDS: 16B-unit column col8 stored at col8^(row&7) -> 2-way max on frag reads.
template <typename TOUT>
__global__ __launch_bounds__(256) void k_gemm_bf(const bf16* __restrict__ X, const bf16* __restrict__ Wm,
                                                 int wStride, TOUT* __restrict__ Out) {
    __shared__ __align__(16) short As[128 * 64];
    __shared__ __align__(16) short Bs[128 * 64];
    int nt = blockIdx.x, ot = blockIdx.y, b = blockIdx.z;
    int n0 = nt * 128, o0 = ot * 128;
    const bf16* xb = X + (size_t)b * NPIX * NC;
    const bf16* Wb = Wm + (size_t)b * wStride;
    int t = threadIdx.x;
    int wv = t >> 6, l = t & 63;
    int wr = wv >> 1, wc = wv & 1;
    f32x4 z4 = {0.f, 0.f, 0.f, 0.f};
    f32x4 acc[4][4];
#pragma unroll
    for (int m = 0; m < 4; ++m)
#pragma unroll
        for (int nf = 0; nf < 4; ++nf) acc[m][nf] = z4;
    for (int kc = 0; kc < 256; kc += 64) {
        __syncthreads();
#pragma unroll
        for (int i = 0; i < 4; ++i) {
            int blk = t + 256 * i;
            int r = blk >> 3, cb = blk & 7;
            int cbs = cb ^ (r & 7);
            *(short8v*)(As + r * 64 + cbs * 8) = *(const short8v*)(Wb + (size_t)(o0 + r) * NC + kc + cb * 8);
            *(short8v*)(Bs + r * 64 + cbs * 8) = *(const short8v*)(xb + (size_t)(n0 + r) * NC + kc + cb * 8);
        }
        __syncthreads();
#pragma unroll
        for (int kk = 0; kk < 2; ++kk) {
            int col8 = kk * 4 + (l >> 4);
            short8v av[4], bv[4];
#pragma unroll
            for (int m = 0; m < 4; ++m) {
                int row = wr * 64 + m * 16 + (l & 15);
                av[m] = *(const short8v*)(As + row * 64 + (col8 ^ (row & 7)) * 8);
            }
#pragma unroll
            for (int nf = 0; nf < 4; ++nf) {
                int row = wc * 64 + nf * 16 + (l & 15);
                bv[nf] = *(const short8v*)(Bs + row * 64 + (col8 ^ (row & 7)) * 8);
            }
#pragma unroll
            for (int m = 0; m < 4; ++m)
#pragma unroll
                for (int nf = 0; nf < 4; ++nf)
                    acc[m][nf] = __builtin_amdgcn_mfma_f32_16x16x32_bf16(av[m], bv[nf], acc[m][nf], 0, 0, 0);
        }
    }
    TOUT* ob = Out + (size_t)b * NC * NPIX;
#pragma unroll
    for (int m = 0; m < 4; ++m)
#pragma unroll
        for (int nf = 0; nf < 4; ++nf)
#pragma unroll
            for (int r = 0; r < 4; ++r) {
                int oo = o0 + wr * 64 + m * 16 + (l >> 4) * 4 + r;
                int nn = n0 + wc * 64 + nf * 16 + (l & 15);
                if constexpr (sizeof(TOUT) == 2)
                    ob[(size_t)oo * NPIX + nn] = __float2bfloat16(acc[m][nf][r]);
                else
                    ob[(size_t)oo * NPIX + nn] = acc[m][nf][r];
            }
}

// ---------------- Gram + fused dw3x3, register-direct ----------------
__device__ inline short8v dw8(const bf16* __restrict__ chan, int r, int cb,
                              const float* __restrict__ w, float& ks) {
    float v[3][10];
#pragma unroll
    for (int ri = 0; ri < 3; ++ri) {
        int r2 = r + ri - 1;
        if (r2 < 0 || r2 >= NH) {
#pragma unroll
            for (int j = 0; j < 10; ++j) v[ri][j] = 0.f;
        } else {
            const bf16* p = chan + (size_t)r2 * NW + cb;
            short8v m = *(const short8v*)p;
            v[ri][0] = (cb > 0) ? __bfloat162float(p[-1]) : 0.f;
#pragma unroll
            for (int j = 0; j < 8; ++j) v[ri][j + 1] = b2f(m[j]);
            v[ri][9] = (cb < 184) ? __bfloat162float(p[8]) : 0.f;
        }
    }
    short8v out;
#pragma unroll
    for (int j = 0; j < 8; ++j) {
        float a = 0.f;
#pragma unroll
        for (int ri = 0; ri < 3; ++ri) {
            a = fmaf(v[ri][j],     w[ri * 3 + 0], a);
            a = fmaf(v[ri][j + 1], w[ri * 3 + 1], a);
            a = fmaf(v[ri][j + 2], w[ri * 3 + 2], a);
        }
        ks = fmaf(a, a, ks);
        out[j] = (short)bfbits(a);
    }
    return out;
}

__global__ __launch_bounds__(256) void k_gram_dw(const bf16* __restrict__ qbf, const bf16* __restrict__ kraw,
                                                 const float* __restrict__ dwW,
                                                 float* __restrict__ gpart, float* __restrict__ ksum) {
    int chunk = blockIdx.x;
    int bh = blockIdx.y; int b = bh >> 3, h = bh & 7;
    const bf16* qb = qbf + ((size_t)b * NC + h * 32) * NPIX;
    const bf16* kb = kraw + ((size_t)b * NC + h * 32) * NPIX;
    __shared__ float sg[4][1024];
    __shared__ float ksh[32];
    int t = threadIdx.x;
    int wv = t >> 6, l = t & 63;
    int dlo = l & 15, kslot = l >> 4;
    float wA[9], wB[9];
#pragma unroll
    for (int i = 0; i < 9; ++i) {
        wA[i] = dwW[(h * 32 + dlo) * 9 + i];
        wB[i] = dwW[(h * 32 + dlo + 16) * 9 + i];
    }
    const bf16* q0 = qb + (size_t)dlo * NPIX;
    const bf16* q1 = qb + (size_t)(dlo + 16) * NPIX;
    const bf16* k0 = kb + (size_t)dlo * NPIX;
    const bf16* k1 = kb + (size_t)(dlo + 16) * NPIX;
    f32x4 z4 = {0.f, 0.f, 0.f, 0.f};
    f32x4 a00 = z4, a01 = z4, a10 = z4, a11 = z4;
    float ks0 = 0.f, ks1 = 0.f;
    int r0 = chunk * 8 + wv * 2;
#pragma unroll
    for (int rr = 0; rr < 2; ++rr) {
        int r = r0 + rr;
#pragma unroll
        for (int c0 = 0; c0 < 192; c0 += 32) {
            int cb = c0 + kslot * 8;
            short8v av0 = *(const short8v*)(q0 + (size_t)r * NW + cb);
            short8v av1 = *(const short8v*)(q1 + (size_t)r * NW + cb);
            short8v bv0 = dw8(k0, r, cb, wA, ks0);
            short8v bv1 = dw8(k1, r, cb, wB, ks1);
            a00 = __builtin_amdgcn_mfma_f32_16x16x32_bf16(av0, bv0, a00, 0, 0, 0);
            a01 = __builtin_amdgcn_mfma_f32_16x16x32_bf16(av0, bv1, a01, 0, 0, 0);
            a10 = __builtin_amdgcn_mfma_f32_16x16x32_bf16(av1, bv0, a10, 0, 0, 0);
            a11 = __builtin_amdgcn_mfma_f32_16x16x32_bf16(av1, bv1, a11, 0, 0, 0);
        }
    }
    if (t < 32) ksh[t] = 0.f;
#pragma unroll
    for (int j = 0; j < 4; ++j) {
        int dA = kslot * 4 + j, dB = 16 + kslot * 4 + j;
        sg[wv][dA * 32 + dlo]      = a00[j];
        sg[wv][dA * 32 + 16 + dlo] = a01[j];
        sg[wv][dB * 32 + dlo]      = a10[j];
        sg[wv][dB * 32 + 16 + dlo] = a11[j];
    }
    __syncthreads();
    float* gp = gpart + ((size_t)bh * GCH + chunk) * 1024;
#pragma unroll
    for (int i = 0; i < 4; ++i) {
        int e = t + 256 * i;
        gp[e] = sg[0][e] + sg[1][e] + sg[2][e] + sg[3][e];
    }
    atomicAdd(&ksh[dlo], ks0);
    atomicAdd(&ksh[dlo + 16], ks1);
    __syncthreads();
    if (t < 32) atomicAdd(&ksum[b * NC + h * 32 + t], ksh[t]);
}

// reduce partials + normalize + temperature + row softmax
__global__ __launch_bounds__(1024) void k_attn(const float* __restrict__ gpart, const float* __restrict__ qsum,
                                               const float* __restrict__ ksum, const float* __restrict__ temp,
                                               float* __restrict__ attn) {
    int bh = blockIdx.x;
    int b = bh >> 3, h = bh & 7;
    int t = threadIdx.x;
    int d = t >> 5, e = t & 31;
    float s = 0.f;
    for (int i = 0; i < GCH; ++i) s += gpart[((size_t)bh * GCH + i) * 1024 + t];
    float rq = 1.f / fmaxf(sqrtf(qsum[b * NC + h * 32 + d]), 1e-12f);
    float rk = 1.f / fmaxf(sqrtf(ksum[b * NC + h * 32 + e]), 1e-12f);
    s *= rq * rk * temp[h];
    float m = s;
#pragma unroll
    for (int off = 16; off; off >>= 1) m = fmaxf(m, __shfl_xor(m, off, 32));
    float ex = expf(s - m);
    float sum = ex;
#pragma unroll
    for (int off = 16; off; off >>= 1) sum += __shfl_xor(sum, off, 32);
    attn[(size_t)bh * 1024 + t] = ex / sum;
}

// fold proj into attn -> bf16
__global__ __launch_bounds__(256) void k_wfold(const float* __restrict__ proj, const float* __restrict__ attn,
                                               bf16* __restrict__ wfbf) {
    int o = blockIdx.x, b = blockIdx.y;
    int t = threadIdx.x;
    int h = t >> 5, e = t & 31;
    const float* ap = attn + (size_t)(b * 8 + h) * 1024 + e;
    const float* pp = proj + o * NC + h * 32;
    float acc = 0.f;
#pragma unroll
    for (int d = 0; d < 32; ++d) acc = fmaf(pp[d], ap[d * 32], acc);
    wfbf[((size_t)b * NC + o) * NC + t] = __float2bfloat16(acc);
}

// ---------------- dw3x3(vraw) + transpose -> v2T [b][n][e] bf16 ----------------
// grid (192 rows, 8 ch-groups of 32, NB). Stage 3 rows x 32 ch (+/-4 col halo) in LDS,
// conv per (e, w), write transposed (e contiguous).
__global__ __launch_bounds__(256) void k_dwv(const bf16* __restrict__ vraw, const float* __restrict__ dwW,
                                             bf16* __restrict__ v2T) {
    int r = blockIdx.x;
    int cg = blockIdx.y;
    int b = blockIdx.z;
    __shared__ short s_v[3][32][204];     // cols 0..199 = global -4..195
    const bf16* vb = vraw + ((size_t)b * NC + cg * 32) * NPIX;
    int t = threadIdx.x;
    for (int idx = t; idx < 4800; idx += 256) {
        int ri = idx / 1600;
        int rem = idx - ri * 1600;
        int e = rem / 50, j = rem - e * 50;
        int gr = r + ri - 1;
        int gc0 = -4 + 4 * j;
        ushort4 u = make_ushort4(0, 0, 0, 0);
        if (gr >= 0 && gr < NH && gc0 >= 0 && gc0 + 3 < NW)
            u = *reinterpret_cast<const ushort4*>(vb + (size_t)e * NPIX + (size_t)gr * NW + gc0);
        *reinterpret_cast<ushort4*>(&s_v[ri][e][4 * j]) = u;
    }
    int e = t & 31;
    int wslot = t >> 5;
    float w9[9];
#pragma unroll
    for (int i = 0; i < 9; ++i) w9[i] = dwW[(256 + cg * 32 + e) * 9 + i];
    __syncthreads();
    bf16* ob = v2T + ((size_t)b * NPIX + (size_t)r * NW) * NC + cg * 32 + e;
#pragma unroll
    for (int wi = 0; wi < 24; ++wi) {
        int w = wslot + 8 * wi;
        int cbase = w + 3;                // staged col of (w-1)
        float a = 0.f;
#pragma unroll
        for (int ri = 0; ri < 3; ++ri) {
            a = fmaf(b2f(s_v[ri][e][cbase]),     w9[ri * 3 + 0], a);
            a = fmaf(b2f(s_v[ri][e][cbase + 1]), w9[ri * 3 + 1], a);
            a = fmaf(b2f(s_v[ri][e][cbase + 2]), w9[ri * 3 + 2], a);
        }
        ob[(size_t)w * NC] = __float2bfloat16(a);
    }
}

// ---------------- launcher ----------------

extern "C" void kernel_launch(void* const* d_in, const int* in_sizes, int n_in,
                              void* d_out, int out_size, void* d_ws, size_t ws_size,
                              hipStream_t stream) {
    (void)in_sizes; (void)n_in; (void)out_size;
    const float* x      = (const float*)d_in[0];
    const float* qkv_w  = (const float*)d_in[1];
    const float* qkv_cw = (const float*)d_in[2];
    const float* w5     = (const float*)d_in[3];
    const float* w7     = (const float*)d_in[4];
    const float* w9     = (const float*)d_in[5];
    const float* projw  = (const float*)d_in[6];
    const float* temp   = (const float*)d_in[7];

    // WS: [0:78.7M] sub -> (dead) -> kraw -> (dead) -> v2T ; [78.7M:] smalls
    const size_t OFF_SM    = 78675968;
    const size_t OFF_WBF   = OFF_SM;                    // 262,144
    const size_t OFF_QSUM  = OFF_SM + 262144;           // 4,096
    const size_t OFF_KSUM  = OFF_QSUM + 4096;           // 4,096
    const size_t OFF_GPART = OFF_KSUM + 4096;           // 3,145,728 (GCH=24)
    const size_t OFF_ATTN  = OFF_GPART + 3145728;       // 131,072
    const size_t OFF_WF    = OFF_ATTN + 131072;         // 524,288
    const size_t WS_NEED   = OFF_WF + 524288;           // 82,747,392
    if (ws_size < WS_NEED) return;

    char* ws = (char*)d_ws;
    bf16*  sub   = (bf16*)ws;
    bf16*  kraw  = (bf16*)ws;
    bf16*  v2T   = (bf16*)ws;
    bf16*  wbf   = (bf16*)(ws + OFF_WBF);
    float* qsum  = (float*)(ws + OFF_QSUM);
    float* ksum  = (float*)(ws + OFF_KSUM);
    float* gpart = (float*)(ws + OFF_GPART);
    float* attn  = (float*)(ws + OFF_ATTN);
    bf16*  wfbf  = (bf16*)(ws + OFF_WF);

    // OUT: xbf [0:75.5M] + qbf [75.5M:151M]; qbf dead after gram -> vraw there;
    // final out overwrites xbf+vraw (both dead by then).
    bf16*  xbf  = (bf16*)d_out;
    bf16*  qbf  = (bf16*)((char*)d_out + 75497472);
    bf16*  vraw = (bf16*)((char*)d_out + 75497472);
    float* out  = (float*)d_out;

    hipMemsetAsync(ws + OFF_QSUM, 0, 8192, stream);   // qsum + ksum

    // wavelet query path
    k_dwt<<<dim3(7, NB * NC), 256, 0, stream>>>(x, sub);
    k_synth2<<<dim3(3, 6, NB * NC), 256, 0, stream>>>(sub, w5, w7, w9, qbf, qsum);

    // shared GEMM inputs
    k_xpose<<<dim3(576, 4, NB), 256, 0, stream>>>(x, xbf);
    k_cvtw<<<512, 256, 0, stream>>>(qkv_w, wbf);

    // k path (kraw overwrites dead sub)
    k_gemm_bf<bf16><<<dim3(288, 2, NB), 256, 0, stream>>>(xbf, wbf, 0, kraw);
    k_gram_dw<<<dim3(GCH, 32), 256, 0, stream>>>(qbf, kraw, qkv_cw, gpart, ksum);

    k_attn<<<32, 1024, 0, stream>>>(gpart, qsum, ksum, temp, attn);
    k_wfold<<<dim3(256, NB), 256, 0, stream>>>(projw, attn, wfbf);

    // v path: GEMM -> vraw (over dead qbf); dw+transpose -> v2T (over dead kraw);
    // final swizzled MFMA GEMM -> out
    k_gemm_bf<bf16><<<dim3(288, 2, NB), 256, 0, stream>>>(xbf, wbf + 256 * 256, 0, vraw);
    k_dwv<<<dim3(NH, 8, NB), 256, 0, stream>>>(vraw, qkv_cw, v2T);
    k_gemm_bf<float><<<dim3(288, 2, NB), 256, 0, stream>>>(v2T, wfbf, 65536, out);
}

// Round 8
// 594.266 us; speedup vs baseline: 1.7428x; 1.0462x over previous
//
#include <hip/hip_runtime.h>
#include <hip/hip_bf16.h>

typedef __hip_bfloat16 bf16;
typedef __attribute__((ext_vector_type(8))) short short8v;   // 8 bf16 = 4 VGPR (MFMA A/B frag)
typedef __attribute__((ext_vector_type(4))) float f32x4;     // MFMA C/D frag

// Problem dims
#define NB 4
#define NC 256
#define NPIX 36864          // 192*192
#define NH 192
#define NW 192
#define SW 98               // db3 subband: (192+8-6)/2+1
#define SH 98
#define GCH 24              // gram row-chunks (8 rows each)

// db3: analysis correlation kernels (pre-flipped dec filters); synthesis G0S=DEC_LO, G1S=DEC_HI
__device__ __constant__ float cH0A[6] = {  0.33267055295095688f,  0.80689150931333875f,  0.45987750211933132f, -0.13501102001039084f, -0.085441273882241486f, 0.035226291882100656f };
__device__ __constant__ float cH1A[6] = {  0.035226291882100656f, 0.085441273882241486f, -0.13501102001039084f, -0.45987750211933132f,  0.80689150931333875f, -0.33267055295095688f };
__device__ __constant__ float cG0S[6] = {  0.035226291882100656f, -0.085441273882241486f, -0.13501102001039084f, 0.45987750211933132f,  0.80689150931333875f,  0.33267055295095688f };
__device__ __constant__ float cG1S[6] = { -0.33267055295095688f,  0.80689150931333875f, -0.45987750211933132f, -0.13501102001039084f,  0.085441273882241486f, 0.035226291882100656f };

__device__ inline unsigned short bfbits(float f) {
    bf16 h = __float2bfloat16(f);
    return *reinterpret_cast<unsigned short*>(&h);
}
__device__ inline float b2f(short s) {
    return __bfloat162float(*reinterpret_cast<const bf16*>(&s));
}
__device__ inline short f2s(float f) {
    bf16 h = __float2bfloat16(f);
    return *reinterpret_cast<short*>(&h);
}

// ---------------- fully-fused wavelet query path: x -> q (+qsum), one kernel ----------------
// Per tile (64w x 32h of q, one (b,c) plane): stage x 44x80, rowDWT -> lo/hi (bf16),
// colDWT -> raw sub (bf16, zeroed outside the 98x98 plane), dw3x3 -> s_c,
// parity col-synth -> s_lh, parity row-synth -> q + qsum.
__global__ __launch_bounds__(256) void k_wave(const float* __restrict__ x,
                                              const float* __restrict__ w5, const float* __restrict__ w7,
                                              const float* __restrict__ w9,
                                              bf16* __restrict__ q, float* __restrict__ qsum) {
    int w0 = blockIdx.x * 64, h0 = blockIdx.y * 32;
    int bc = blockIdx.z;
    int c = bc & 255;
    int jh0 = h0 >> 1, jw0 = w0 >> 1;
    int xr0 = 2 * jh0 - 6;               // global image row of s_x row 0
    int xc0 = 2 * jw0 - 8;               // global image col of s_x col 0
    __shared__ float s_x[44][80];
    __shared__ short s_lo[44][38];
    __shared__ short s_hi[44][38];
    __shared__ short s_sub[4][20][38];   // raw sub rows jh0-1.., cols jw0-2..
    __shared__ float s_c[4][18][34];     // conv'd: rows jh0.., cols jw0..
    __shared__ float s_lh[2][32][34];
    __shared__ float s_w[4][9];
    __shared__ float red[4];
    const float* xp = x + (size_t)bc * NPIX;
    int t = threadIdx.x;
    if (t < 36) {
        int f = t / 9, k = t - f * 9;
        const float* wsel = (f <= 1) ? w5 : (f == 2 ? w7 : w9);
        s_w[f][k] = wsel[c * 9 + k];
    }
    // phase 1: stage x (44 rows x 20 float4), zero-fill OOB
    for (int e = t; e < 880; e += 256) {
        int r = e / 20, s = e - r * 20;
        int row = xr0 + r, col0 = xc0 + s * 4;
        float4 v = make_float4(0.f, 0.f, 0.f, 0.f);
        if (row >= 0 && row < NH) {
            if (col0 >= 0 && col0 + 3 < NW) {
                v = *reinterpret_cast<const float4*>(xp + (size_t)row * NW + col0);
            } else {
#pragma unroll
                for (int j = 0; j < 4; ++j) {
                    int cc = col0 + j;
                    if (cc >= 0 && cc < NW) (&v.x)[j] = xp[(size_t)row * NW + cc];
                }
            }
        }
        *reinterpret_cast<float4*>(&s_x[r][s * 4]) = v;
    }
    __syncthreads();
    // phase 2: row DWT -> lo/hi (44 x 38), no bounds checks (zeros staged)
    for (int e = t; e < 1672; e += 256) {
        int r = e / 38, jc = e - r * 38;
        float la = 0.f, ha = 0.f;
#pragma unroll
        for (int tp = 0; tp < 6; ++tp) {
            float v = s_x[r][2 * jc + tp];
            la = fmaf(v, cH0A[tp], la);
            ha = fmaf(v, cH1A[tp], ha);
        }
        s_lo[r][jc] = f2s(la); s_hi[r][jc] = f2s(ha);
    }
    __syncthreads();
    // phase 3: col DWT -> raw sub (20 x 38), zero outside the 98x98 plane
    for (int e = t; e < 760; e += 256) {
        int r = e / 38, jc = e - r * 38;
        int gr = jh0 - 1 + r, gcol = jw0 - 2 + jc;
        bool inb = (gr >= 0 && gr < SH && gcol >= 0 && gcol < SW);
        float ll = 0.f, lh = 0.f, hl = 0.f, hh = 0.f;
#pragma unroll
        for (int tp = 0; tp < 6; ++tp) {
            float lv = b2f(s_lo[2 * r + tp][jc]);
            float hv = b2f(s_hi[2 * r + tp][jc]);
            ll = fmaf(lv, cH0A[tp], ll); lh = fmaf(lv, cH1A[tp], lh);
            hl = fmaf(hv, cH0A[tp], hl); hh = fmaf(hv, cH1A[tp], hh);
        }
        s_sub[0][r][jc] = inb ? f2s(ll) : (short)0;
        s_sub[1][r][jc] = inb ? f2s(lh) : (short)0;
        s_sub[2][r][jc] = inb ? f2s(hl) : (short)0;
        s_sub[3][r][jc] = inb ? f2s(hh) : (short)0;
    }
    float ge0[3] = { cG0S[1], cG0S[3], cG0S[5] };
    float go0[3] = { cG0S[0], cG0S[2], cG0S[4] };
    float ge1[3] = { cG1S[1], cG1S[3], cG1S[5] };
    float go1[3] = { cG1S[0], cG1S[2], cG1S[4] };
    __syncthreads();
    // phase 4: depthwise 3x3 on the 4 subband planes -> s_c (4 x 18 x 34)
    for (int e = t; e < 2448; e += 256) {
        int pl = e / 612;
        int r2 = e - pl * 612;
        int r = r2 / 34, cc = r2 - r * 34;
        const float* wp = s_w[pl];
        float a = 0.f;
#pragma unroll
        for (int ky = 0; ky < 3; ++ky)
#pragma unroll
            for (int kx = 0; kx < 3; ++kx)
                a = fmaf(b2f(s_sub[pl][r + ky][cc + 1 + kx]), wp[ky * 3 + kx], a);
        s_c[pl][r][cc] = a;
    }
    __syncthreads();
    // phase 5: parity col synthesis -> s_lh (2 x 32 x 34)
    for (int e = t; e < 2176; e += 256) {
        int which = e / 1088;
        int r2 = e - which * 1088;
        int hh = r2 / 34, cc = r2 - hh * 34;
        int par = hh & 1;
        int j0 = hh >> 1;
        float a = 0.f;
#pragma unroll
        for (int i = 0; i < 3; ++i) {
            float g0 = par ? go0[i] : ge0[i];
            float g1 = par ? go1[i] : ge1[i];
            a = fmaf(s_c[2 * which][j0 + i][cc], g0, a);
            a = fmaf(s_c[2 * which + 1][j0 + i][cc], g1, a);
        }
        s_lh[which][hh][cc] = a;
    }
    __syncthreads();
    // phase 6: parity row synthesis -> q + sum(q^2)
    float lsum = 0.f;
    bf16* qp = q + (size_t)bc * NPIX;
#pragma unroll
    for (int it = 0; it < 8; ++it) {
        int e = t + 256 * it;
        int hh = e >> 6, ww = e & 63;
        int par = ww & 1;
        int j0 = ww >> 1;
        float a = 0.f;
#pragma unroll
        for (int i = 0; i < 3; ++i) {
            float g0 = par ? go0[i] : ge0[i];
            float g1 = par ? go1[i] : ge1[i];
            a = fmaf(s_lh[0][hh][j0 + i], g0, a);
            a = fmaf(s_lh[1][hh][j0 + i], g1, a);
        }
        qp[(size_t)(h0 + hh) * NW + w0 + ww] = __float2bfloat16(a);
        lsum = fmaf(a, a, lsum);
    }
#pragma unroll
    for (int off = 32; off; off >>= 1) lsum += __shfl_down(lsum, off, 64);
    if ((t & 63) == 0) red[t >> 6] = lsum;
    __syncthreads();
    if (t == 0) atomicAdd(&qsum[bc], red[0] + red[1] + red[2] + red[3]);
}

// ---------------- transpose-convert: x [b][c][n] f32 -> xT [b][n][c] bf16 ----------------
__global__ __launch_bounds__(256) void k_xpose(const float* __restrict__ x, bf16* __restrict__ xT) {
    __shared__ float T[64][68];
    int nt = blockIdx.x, ct = blockIdx.y, b = blockIdx.z;
    int n0 = nt * 64, c0 = ct * 64;
    const float* xb = x + ((size_t)b * NC + c0) * NPIX + n0;
    int t = threadIdx.x;
    int tr = t >> 4, tc4 = (t & 15) * 4;
#pragma unroll
    for (int i = 0; i < 4; ++i) {
        int cc = tr + i * 16;
        float4 v = *reinterpret_cast<const float4*>(xb + (size_t)cc * NPIX + tc4);
        T[cc][tc4] = v.x; T[cc][tc4 + 1] = v.y; T[cc][tc4 + 2] = v.z; T[cc][tc4 + 3] = v.w;
    }
    __syncthreads();
    bf16* ob = xT + ((size_t)b * NPIX + n0) * NC + c0;
#pragma unroll
    for (int i = 0; i < 4; ++i) {
        int nn = tr + i * 16;
        ushort4 u;
        u.x = bfbits(T[tc4][nn]); u.y = bfbits(T[tc4 + 1][nn]);
        u.z = bfbits(T[tc4 + 2][nn]); u.w = bfbits(T[tc4 + 3][nn]);
        *reinterpret_cast<ushort4*>(ob + (size_t)nn * NC + tc4) = u;
    }
}

// convert qkv_w (512x256 f32) -> bf16
__global__ __launch_bounds__(256) void k_cvtw(const float* __restrict__ w, bf16* __restrict__ wb) {
    int idx = blockIdx.x * 256 + threadIdx.x;
    if (idx < 512 * 256) wb[idx] = __float2bfloat16(w[idx]);
}

// ---------------- MFMA GEMM: Out[b,o,n] = sum_k W[(b),o,k] * X[b,n,k]  (128x128 tile) ----------------
// T2 XOR-swizzle on LDS: 16B-unit column col8 stored at col8^(row&7) -> 2-way max on frag reads.
template <typename TOUT>
__global__ __launch_bounds__(256) void k_gemm_bf(const bf16* __restrict__ X, const bf16* __restrict__ Wm,
                                                 int wStride, TOUT* __restrict__ Out) {
    __shared__ __align__(16) short As[128 * 64];
    __shared__ __align__(16) short Bs[128 * 64];
    int nt = blockIdx.x, ot = blockIdx.y, b = blockIdx.z;
    int n0 = nt * 128, o0 = ot * 128;
    const bf16* xb = X + (size_t)b * NPIX * NC;
    const bf16* Wb = Wm + (size_t)b * wStride;
    int t = threadIdx.x;
    int wv = t >> 6, l = t & 63;
    int wr = wv >> 1, wc = wv & 1;
    f32x4 z4 = {0.f, 0.f, 0.f, 0.f};
    f32x4 acc[4][4];
#pragma unroll
    for (int m = 0; m < 4; ++m)
#pragma unroll
        for (int nf = 0; nf < 4; ++nf) acc[m][nf] = z4;
    for (int kc = 0; kc < 256; kc += 64) {
        __syncthreads();
#pragma unroll
        for (int i = 0; i < 4; ++i) {
            int blk = t + 256 * i;
            int r = blk >> 3, cb = blk & 7;
            int cbs = cb ^ (r & 7);
            *(short8v*)(As + r * 64 + cbs * 8) = *(const short8v*)(Wb + (size_t)(o0 + r) * NC + kc + cb * 8);
            *(short8v*)(Bs + r * 64 + cbs * 8) = *(const short8v*)(xb + (size_t)(n0 + r) * NC + kc + cb * 8);
        }
        __syncthreads();
#pragma unroll
        for (int kk = 0; kk < 2; ++kk) {
            int col8 = kk * 4 + (l >> 4);
            short8v av[4], bv[4];
#pragma unroll
            for (int m = 0; m < 4; ++m) {
                int row = wr * 64 + m * 16 + (l & 15);
                av[m] = *(const short8v*)(As + row * 64 + (col8 ^ (row & 7)) * 8);
            }
#pragma unroll
            for (int nf = 0; nf < 4; ++nf) {
                int row = wc * 64 + nf * 16 + (l & 15);
                bv[nf] = *(const short8v*)(Bs + row * 64 + (col8 ^ (row & 7)) * 8);
            }
#pragma unroll
            for (int m = 0; m < 4; ++m)
#pragma unroll
                for (int nf = 0; nf < 4; ++nf)
                    acc[m][nf] = __builtin_amdgcn_mfma_f32_16x16x32_bf16(av[m], bv[nf], acc[m][nf], 0, 0, 0);
        }
    }
    TOUT* ob = Out + (size_t)b * NC * NPIX;
#pragma unroll
    for (int m = 0; m < 4; ++m)
#pragma unroll
        for (int nf = 0; nf < 4; ++nf)
#pragma unroll
            for (int r = 0; r < 4; ++r) {
                int oo = o0 + wr * 64 + m * 16 + (l >> 4) * 4 + r;
                int nn = n0 + wc * 64 + nf * 16 + (l & 15);
                if constexpr (sizeof(TOUT) == 2)
                    ob[(size_t)oo * NPIX + nn] = __float2bfloat16(acc[m][nf][r]);
                else
                    ob[(size_t)oo * NPIX + nn] = acc[m][nf][r];
            }
}

// ---------------- Gram + fused dw3x3, register-direct ----------------
__device__ inline short8v dw8(const bf16* __restrict__ chan, int r, int cb,
                              const float* __restrict__ w, float& ks) {
    float v[3][10];
#pragma unroll
    for (int ri = 0; ri < 3; ++ri) {
        int r2 = r + ri - 1;
        if (r2 < 0 || r2 >= NH) {
#pragma unroll
            for (int j = 0; j < 10; ++j) v[ri][j] = 0.f;
        } else {
            const bf16* p = chan + (size_t)r2 * NW + cb;
            short8v m = *(const short8v*)p;
            v[ri][0] = (cb > 0) ? __bfloat162float(p[-1]) : 0.f;
#pragma unroll
            for (int j = 0; j < 8; ++j) v[ri][j + 1] = b2f(m[j]);
            v[ri][9] = (cb < 184) ? __bfloat162float(p[8]) : 0.f;
        }
    }
    short8v out;
#pragma unroll
    for (int j = 0; j < 8; ++j) {
        float a = 0.f;
#pragma unroll
        for (int ri = 0; ri < 3; ++ri) {
            a = fmaf(v[ri][j],     w[ri * 3 + 0], a);
            a = fmaf(v[ri][j + 1], w[ri * 3 + 1], a);
            a = fmaf(v[ri][j + 2], w[ri * 3 + 2], a);
        }
        ks = fmaf(a, a, ks);
        out[j] = (short)bfbits(a);
    }
    return out;
}

__global__ __launch_bounds__(256) void k_gram_dw(const bf16* __restrict__ qbf, const bf16* __restrict__ kraw,
                                                 const float* __restrict__ dwW,
                                                 float* __restrict__ gpart, float* __restrict__ ksum) {
    int chunk = blockIdx.x;
    int bh = blockIdx.y; int b = bh >> 3, h = bh & 7;
    const bf16* qb = qbf + ((size_t)b * NC + h * 32) * NPIX;
    const bf16* kb = kraw + ((size_t)b * NC + h * 32) * NPIX;
    __shared__ float sg[4][1024];
    __shared__ float ksh[32];
    int t = threadIdx.x;
    int wv = t >> 6, l = t & 63;
    int dlo = l & 15, kslot = l >> 4;
    float wA[9], wB[9];
#pragma unroll
    for (int i = 0; i < 9; ++i) {
        wA[i] = dwW[(h * 32 + dlo) * 9 + i];
        wB[i] = dwW[(h * 32 + dlo + 16) * 9 + i];
    }
    const bf16* q0 = qb + (size_t)dlo * NPIX;
    const bf16* q1 = qb + (size_t)(dlo + 16) * NPIX;
    const bf16* k0 = kb + (size_t)dlo * NPIX;
    const bf16* k1 = kb + (size_t)(dlo + 16) * NPIX;
    f32x4 z4 = {0.f, 0.f, 0.f, 0.f};
    f32x4 a00 = z4, a01 = z4, a10 = z4, a11 = z4;
    float ks0 = 0.f, ks1 = 0.f;
    int r0 = chunk * 8 + wv * 2;
#pragma unroll
    for (int rr = 0; rr < 2; ++rr) {
        int r = r0 + rr;
#pragma unroll
        for (int c0 = 0; c0 < 192; c0 += 32) {
            int cb = c0 + kslot * 8;
            short8v av0 = *(const short8v*)(q0 + (size_t)r * NW + cb);
            short8v av1 = *(const short8v*)(q1 + (size_t)r * NW + cb);
            short8v bv0 = dw8(k0, r, cb, wA, ks0);
            short8v bv1 = dw8(k1, r, cb, wB, ks1);
            a00 = __builtin_amdgcn_mfma_f32_16x16x32_bf16(av0, bv0, a00, 0, 0, 0);
            a01 = __builtin_amdgcn_mfma_f32_16x16x32_bf16(av0, bv1, a01, 0, 0, 0);
            a10 = __builtin_amdgcn_mfma_f32_16x16x32_bf16(av1, bv0, a10, 0, 0, 0);
            a11 = __builtin_amdgcn_mfma_f32_16x16x32_bf16(av1, bv1, a11, 0, 0, 0);
        }
    }
    if (t < 32) ksh[t] = 0.f;
#pragma unroll
    for (int j = 0; j < 4; ++j) {
        int dA = kslot * 4 + j, dB = 16 + kslot * 4 + j;
        sg[wv][dA * 32 + dlo]      = a00[j];
        sg[wv][dA * 32 + 16 + dlo] = a01[j];
        sg[wv][dB * 32 + dlo]      = a10[j];
        sg[wv][dB * 32 + 16 + dlo] = a11[j];
    }
    __syncthreads();
    float* gp = gpart + ((size_t)bh * GCH + chunk) * 1024;
#pragma unroll
    for (int i = 0; i < 4; ++i) {
        int e = t + 256 * i;
        gp[e] = sg[0][e] + sg[1][e] + sg[2][e] + sg[3][e];
    }
    atomicAdd(&ksh[dlo], ks0);
    atomicAdd(&ksh[dlo + 16], ks1);
    __syncthreads();
    if (t < 32) atomicAdd(&ksum[b * NC + h * 32 + t], ksh[t]);
}

// reduce partials + normalize + temperature + row softmax
__global__ __launch_bounds__(1024) void k_attn(const float* __restrict__ gpart, const float* __restrict__ qsum,
                                               const float* __restrict__ ksum, const float* __restrict__ temp,
                                               float* __restrict__ attn) {
    int bh = blockIdx.x;
    int b = bh >> 3, h = bh & 7;
    int t = threadIdx.x;
    int d = t >> 5, e = t & 31;
    float s = 0.f;
    for (int i = 0; i < GCH; ++i) s += gpart[((size_t)bh * GCH + i) * 1024 + t];
    float rq = 1.f / fmaxf(sqrtf(qsum[b * NC + h * 32 + d]), 1e-12f);
    float rk = 1.f / fmaxf(sqrtf(ksum[b * NC + h * 32 + e]), 1e-12f);
    s *= rq * rk * temp[h];
    float m = s;
#pragma unroll
    for (int off = 16; off; off >>= 1) m = fmaxf(m, __shfl_xor(m, off, 32));
    float ex = expf(s - m);
    float sum = ex;
#pragma unroll
    for (int off = 16; off; off >>= 1) sum += __shfl_xor(sum, off, 32);
    attn[(size_t)bh * 1024 + t] = ex / sum;
}

// fold proj into attn -> bf16
__global__ __launch_bounds__(256) void k_wfold(const float* __restrict__ proj, const float* __restrict__ attn,
                                               bf16* __restrict__ wfbf) {
    int o = blockIdx.x, b = blockIdx.y;
    int t = threadIdx.x;
    int h = t >> 5, e = t & 31;
    const float* ap = attn + (size_t)(b * 8 + h) * 1024 + e;
    const float* pp = proj + o * NC + h * 32;
    float acc = 0.f;
#pragma unroll
    for (int d = 0; d < 32; ++d) acc = fmaf(pp[d], ap[d * 32], acc);
    wfbf[((size_t)b * NC + o) * NC + t] = __float2bfloat16(acc);
}

// ---------------- dw3x3(vraw) + transpose -> v2T [b][n][e] bf16 ----------------
__global__ __launch_bounds__(256) void k_dwv(const bf16* __restrict__ vraw, const float* __restrict__ dwW,
                                             bf16* __restrict__ v2T) {
    int r = blockIdx.x;
    int cg = blockIdx.y;
    int b = blockIdx.z;
    __shared__ short s_v[3][32][204];     // cols 0..199 = global -4..195
    const bf16* vb = vraw + ((size_t)b * NC + cg * 32) * NPIX;
    int t = threadIdx.x;
    for (int idx = t; idx < 4800; idx += 256) {
        int ri = idx / 1600;
        int rem = idx - ri * 1600;
        int e = rem / 50, j = rem - e * 50;
        int gr = r + ri - 1;
        int gc0 = -4 + 4 * j;
        ushort4 u = make_ushort4(0, 0, 0, 0);
        if (gr >= 0 && gr < NH && gc0 >= 0 && gc0 + 3 < NW)
            u = *reinterpret_cast<const ushort4*>(vb + (size_t)e * NPIX + (size_t)gr * NW + gc0);
        *reinterpret_cast<ushort4*>(&s_v[ri][e][4 * j]) = u;
    }
    int e = t & 31;
    int wslot = t >> 5;
    float w9[9];
#pragma unroll
    for (int i = 0; i < 9; ++i) w9[i] = dwW[(256 + cg * 32 + e) * 9 + i];
    __syncthreads();
    bf16* ob = v2T + ((size_t)b * NPIX + (size_t)r * NW) * NC + cg * 32 + e;
#pragma unroll
    for (int wi = 0; wi < 24; ++wi) {
        int w = wslot + 8 * wi;
        int cbase = w + 3;                // staged col of (w-1)
        float a = 0.f;
#pragma unroll
        for (int ri = 0; ri < 3; ++ri) {
            a = fmaf(b2f(s_v[ri][e][cbase]),     w9[ri * 3 + 0], a);
            a = fmaf(b2f(s_v[ri][e][cbase + 1]), w9[ri * 3 + 1], a);
            a = fmaf(b2f(s_v[ri][e][cbase + 2]), w9[ri * 3 + 2], a);
        }
        ob[(size_t)w * NC] = __float2bfloat16(a);
    }
}

// ---------------- launcher ----------------

extern "C" void kernel_launch(void* const* d_in, const int* in_sizes, int n_in,
                              void* d_out, int out_size, void* d_ws, size_t ws_size,
                              hipStream_t stream) {
    (void)in_sizes; (void)n_in; (void)out_size;
    const float* x      = (const float*)d_in[0];
    const float* qkv_w  = (const float*)d_in[1];
    const float* qkv_cw = (const float*)d_in[2];
    const float* w5     = (const float*)d_in[3];
    const float* w7     = (const float*)d_in[4];
    const float* w9     = (const float*)d_in[5];
    const float* projw  = (const float*)d_in[6];
    const float* temp   = (const float*)d_in[7];

    // WS: [0:78.7M] kraw -> (dead) -> v2T ; [78.7M:] smalls
    const size_t OFF_SM    = 78675968;
    const size_t OFF_WBF   = OFF_SM;                    // 262,144
    const size_t OFF_QSUM  = OFF_SM + 262144;           // 4,096
    const size_t OFF_KSUM  = OFF_QSUM + 4096;           // 4,096
    const size_t OFF_GPART = OFF_KSUM + 4096;           // 3,145,728 (GCH=24)
    const size_t OFF_ATTN  = OFF_GPART + 3145728;       // 131,072
    const size_t OFF_WF    = OFF_ATTN + 131072;         // 524,288
    const size_t WS_NEED   = OFF_WF + 524288;           // 82,747,392
    if (ws_size < WS_NEED) return;

    char* ws = (char*)d_ws;
    bf16*  kraw  = (bf16*)ws;
    bf16*  v2T   = (bf16*)ws;
    bf16*  wbf   = (bf16*)(ws + OFF_WBF);
    float* qsum  = (float*)(ws + OFF_QSUM);
    float* ksum  = (float*)(ws + OFF_KSUM);
    float* gpart = (float*)(ws + OFF_GPART);
    float* attn  = (float*)(ws + OFF_ATTN);
    bf16*  wfbf  = (bf16*)(ws + OFF_WF);

    // OUT: xbf [0:75.5M] + qbf [75.5M:151M]; qbf dead after gram -> vraw there;
    // final out overwrites xbf+vraw (both dead by then).
    bf16*  xbf  = (bf16*)d_out;
    bf16*  qbf  = (bf16*)((char*)d_out + 75497472);
    bf16*  vraw = (bf16*)((char*)d_out + 75497472);
    float* out  = (float*)d_out;

    hipMemsetAsync(ws + OFF_QSUM, 0, 8192, stream);   // qsum + ksum

    // wavelet query path: single fused kernel x -> qbf + qsum
    k_wave<<<dim3(3, 6, NB * NC), 256, 0, stream>>>(x, w5, w7, w9, qbf, qsum);

    // shared GEMM inputs
    k_xpose<<<dim3(576, 4, NB), 256, 0, stream>>>(x, xbf);
    k_cvtw<<<512, 256, 0, stream>>>(qkv_w, wbf);

    // k path
    k_gemm_bf<bf16><<<dim3(288, 2, NB), 256, 0, stream>>>(xbf, wbf, 0, kraw);
    k_gram_dw<<<dim3(GCH, 32), 256, 0, stream>>>(qbf, kraw, qkv_cw, gpart, ksum);

    k_attn<<<32, 1024, 0, stream>>>(gpart, qsum, ksum, temp, attn);
    k_wfold<<<dim3(256, NB), 256, 0, stream>>>(projw, attn, wfbf);

    // v path
    k_gemm_bf<bf16><<<dim3(288, 2, NB), 256, 0, stream>>>(xbf, wbf + 256 * 256, 0, vraw);
    k_dwv<<<dim3(NH, 8, NB), 256, 0, stream>>>(vraw, qkv_cw, v2T);
    k_gemm_bf<float><<<dim3(288, 2, NB), 256, 0, stream>>>(v2T, wfbf, 65536, out);
}

// Round 9
// 536.594 us; speedup vs baseline: 1.9301x; 1.1075x over previous
//
#include <hip/hip_runtime.h>
#include <hip/hip_bf16.h>

typedef __hip_bfloat16 bf16;
typedef __attribute__((ext_vector_type(8))) short short8v;   // 8 bf16 = 4 VGPR (MFMA A/B frag)
typedef __attribute__((ext_vector_type(4))) float f32x4;     // MFMA C/D frag

// Problem dims
#define NB 4
#define NC 256
#define NPIX 36864          // 192*192
#define NH 192
#define NW 192
#define SW 98               // db3 subband: (192+8-6)/2+1
#define SH 98
#define GCH 24              // gram row-chunks (8 rows each)

// db3: analysis correlation kernels (pre-flipped dec filters); synthesis G0S=DEC_LO, G1S=DEC_HI
__device__ __constant__ float cH0A[6] = {  0.33267055295095688f,  0.80689150931333875f,  0.45987750211933132f, -0.13501102001039084f, -0.085441273882241486f, 0.035226291882100656f };
__device__ __constant__ float cH1A[6] = {  0.035226291882100656f, 0.085441273882241486f, -0.13501102001039084f, -0.45987750211933132f,  0.80689150931333875f, -0.33267055295095688f };
__device__ __constant__ float cG0S[6] = {  0.035226291882100656f, -0.085441273882241486f, -0.13501102001039084f, 0.45987750211933132f,  0.80689150931333875f,  0.33267055295095688f };
__device__ __constant__ float cG1S[6] = { -0.33267055295095688f,  0.80689150931333875f, -0.45987750211933132f, -0.13501102001039084f,  0.085441273882241486f, 0.035226291882100656f };

__device__ inline unsigned short bfbits(float f) {
    bf16 h = __float2bfloat16(f);
    return *reinterpret_cast<unsigned short*>(&h);
}
__device__ inline float b2f(short s) {
    return __bfloat162float(*reinterpret_cast<const bf16*>(&s));
}

// ---------------- fully-fused wavelet query path: x -> q (+qsum), one kernel ----------------
// Per tile (64w x 32h of q, one (b,c) plane). All-f32 LDS; regions unioned by liveness:
//   region1 [0:14080)      : s_x (ph1-2)   then s_c (ph4-5)
//   region2 [14080:28160)  : s_lo|s_hi (ph2-3) then s_lh (ph5-6)
//   region3 [28160:40320)  : s_sub (ph3-4)
__global__ __launch_bounds__(256) void k_wave(const float* __restrict__ x,
                                              const float* __restrict__ w5, const float* __restrict__ w7,
                                              const float* __restrict__ w9,
                                              bf16* __restrict__ q, float* __restrict__ qsum) {
    int w0 = blockIdx.x * 64, h0 = blockIdx.y * 32;
    int bc = blockIdx.z;
    int c = bc & 255;
    int jh0 = h0 >> 1, jw0 = w0 >> 1;
    int xr0 = h0 - 6;               // 2*jh0-6: global image row of s_x row 0
    int xc0 = w0 - 8;               // 2*jw0-8: global image col of s_x col 0
    __shared__ __align__(16) char smem[40320];
    float (*s_x)[80]   = (float(*)[80])smem;               // [44][80]
    float (*s_c)[36]   = (float(*)[36])smem;               // [72][36] = [4*18][36]
    float (*s_lo)[40]  = (float(*)[40])(smem + 14080);     // [44][40]
    float (*s_hi)[40]  = (float(*)[40])(smem + 21120);     // [44][40]
    float (*s_lh)[36]  = (float(*)[36])(smem + 14080);     // [64][36] = [2*32][36]
    float (*s_sub)[38] = (float(*)[38])(smem + 28160);     // [80][38] = [4*20][38]
    __shared__ float s_w[4][9];
    __shared__ float red[4];
    const float* xp = x + (size_t)bc * NPIX;
    int t = threadIdx.x;
    if (t < 36) {
        int f = t / 9, k = t - f * 9;
        const float* wsel = (f <= 1) ? w5 : (f == 2 ? w7 : w9);
        s_w[f][k] = wsel[c * 9 + k];
    }
    // phase 1: stage x (44 rows x 20 float4), zero-fill OOB
    for (int e = t; e < 880; e += 256) {
        int r = e / 20, s = e - r * 20;
        int row = xr0 + r, col0 = xc0 + s * 4;
        float4 v = make_float4(0.f, 0.f, 0.f, 0.f);
        if (row >= 0 && row < NH) {
            if (col0 >= 0 && col0 + 3 < NW) {
                v = *reinterpret_cast<const float4*>(xp + (size_t)row * NW + col0);
            } else {
#pragma unroll
                for (int j = 0; j < 4; ++j) {
                    int cc = col0 + j;
                    if (cc >= 0 && cc < NW) (&v.x)[j] = xp[(size_t)row * NW + cc];
                }
            }
        }
        *reinterpret_cast<float4*>(&s_x[r][s * 4]) = v;
    }
    __syncthreads();
    // phase 2: row DWT -> s_lo/s_hi (44 x 38), f32
    for (int e = t; e < 1672; e += 256) {
        int r = e / 38, jc = e - r * 38;
        float la = 0.f, ha = 0.f;
#pragma unroll
        for (int tp = 0; tp < 6; ++tp) {
            float v = s_x[r][2 * jc + tp];
            la = fmaf(v, cH0A[tp], la);
            ha = fmaf(v, cH1A[tp], ha);
        }
        s_lo[r][jc] = la; s_hi[r][jc] = ha;
    }
    __syncthreads();
    // phase 3: col DWT -> raw sub (4 x 20 x 38), f32, zeroed outside the 98x98 plane
    for (int e = t; e < 760; e += 256) {
        int r = e / 38, jc = e - r * 38;
        int gr = jh0 - 1 + r, gcol = jw0 - 2 + jc;
        bool inb = (gr >= 0 && gr < SH && gcol >= 0 && gcol < SW);
        float ll = 0.f, lh = 0.f, hl = 0.f, hh = 0.f;
#pragma unroll
        for (int tp = 0; tp < 6; ++tp) {
            float lv = s_lo[2 * r + tp][jc];
            float hv = s_hi[2 * r + tp][jc];
            ll = fmaf(lv, cH0A[tp], ll); lh = fmaf(lv, cH1A[tp], lh);
            hl = fmaf(hv, cH0A[tp], hl); hh = fmaf(hv, cH1A[tp], hh);
        }
        s_sub[r][jc]      = inb ? ll : 0.f;
        s_sub[20 + r][jc] = inb ? lh : 0.f;
        s_sub[40 + r][jc] = inb ? hl : 0.f;
        s_sub[60 + r][jc] = inb ? hh : 0.f;
    }
    __syncthreads();
    // phase 4: depthwise 3x3 on the 4 subband planes -> s_c (72 x 34 used)
    for (int e = t; e < 2448; e += 256) {
        int pr = e / 34, cc = e - pr * 34;     // pr = pl*18 + r
        int pl = pr / 18, r = pr - pl * 18;
        const float* wp = s_w[pl];
        const int rb = pl * 20 + r;            // s_sub row base (halo -1 built in: +ky)
        float a = 0.f;
#pragma unroll
        for (int ky = 0; ky < 3; ++ky)
#pragma unroll
            for (int kx = 0; kx < 3; ++kx)
                a = fmaf(s_sub[rb + ky][cc + 1 + kx], wp[ky * 3 + kx], a);
        s_c[pr][cc] = a;
    }
    __syncthreads();
    // phase 5: paired col synthesis -> s_lh (64 x 34 used). Rows 2m,2m+1 share j0=m and taps
    // split by parity at compile time (G0S/G1S odd/even subsets).
    for (int e = t; e < 1088; e += 256) {
        int row = e / 34, cc = e - row * 34;   // row = which*16 + m
        int which = row >> 4, m = row & 15;
        float c0_0 = s_c[which * 36 + m][cc],     c1_0 = s_c[which * 36 + 18 + m][cc];
        float c0_1 = s_c[which * 36 + m + 1][cc], c1_1 = s_c[which * 36 + 18 + m + 1][cc];
        float c0_2 = s_c[which * 36 + m + 2][cc], c1_2 = s_c[which * 36 + 18 + m + 2][cc];
        float ae = c0_0 * cG0S[1] + c0_1 * cG0S[3] + c0_2 * cG0S[5]
                 + c1_0 * cG1S[1] + c1_1 * cG1S[3] + c1_2 * cG1S[5];
        float ao = c0_0 * cG0S[0] + c0_1 * cG0S[2] + c0_2 * cG0S[4]
                 + c1_0 * cG1S[0] + c1_1 * cG1S[2] + c1_2 * cG1S[4];
        s_lh[which * 32 + 2 * m][cc] = ae;
        s_lh[which * 32 + 2 * m + 1][cc] = ao;
    }
    __syncthreads();
    // phase 6: paired row synthesis -> q (packed 2xbf16 stores) + sum(q^2)
    float lsum = 0.f;
    bf16* qp = q + (size_t)bc * NPIX;
#pragma unroll
    for (int it = 0; it < 4; ++it) {
        int e = t + 256 * it;
        int hh = e >> 5, m = e & 31;
        float l0 = s_lh[hh][m],     h0v = s_lh[32 + hh][m];
        float l1 = s_lh[hh][m + 1], h1v = s_lh[32 + hh][m + 1];
        float l2 = s_lh[hh][m + 2], h2v = s_lh[32 + hh][m + 2];
        float ae = l0 * cG0S[1] + l1 * cG0S[3] + l2 * cG0S[5]
                 + h0v * cG1S[1] + h1v * cG1S[3] + h2v * cG1S[5];
        float ao = l0 * cG0S[0] + l1 * cG0S[2] + l2 * cG0S[4]
                 + h0v * cG1S[0] + h1v * cG1S[2] + h2v * cG1S[4];
        unsigned pack = (unsigned)bfbits(ae) | ((unsigned)bfbits(ao) << 16);
        *reinterpret_cast<unsigned*>(qp + (size_t)(h0 + hh) * NW + w0 + 2 * m) = pack;
        lsum = fmaf(ae, ae, lsum);
        lsum = fmaf(ao, ao, lsum);
    }
#pragma unroll
    for (int off = 32; off; off >>= 1) lsum += __shfl_down(lsum, off, 64);
    if ((t & 63) == 0) red[t >> 6] = lsum;
    __syncthreads();
    if (t == 0) atomicAdd(&qsum[bc], red[0] + red[1] + red[2] + red[3]);
}

// ---------------- transpose-convert: x [b][c][n] f32 -> xT [b][n][c] bf16 ----------------
__global__ __launch_bounds__(256) void k_xpose(const float* __restrict__ x, bf16* __restrict__ xT) {
    __shared__ float T[64][68];
    int nt = blockIdx.x, ct = blockIdx.y, b = blockIdx.z;
    int n0 = nt * 64, c0 = ct * 64;
    const float* xb = x + ((size_t)b * NC + c0) * NPIX + n0;
    int t = threadIdx.x;
    int tr = t >> 4, tc4 = (t & 15) * 4;
#pragma unroll
    for (int i = 0; i < 4; ++i) {
        int cc = tr + i * 16;
        float4 v = *reinterpret_cast<const float4*>(xb + (size_t)cc * NPIX + tc4);
        T[cc][tc4] = v.x; T[cc][tc4 + 1] = v.y; T[cc][tc4 + 2] = v.z; T[cc][tc4 + 3] = v.w;
    }
    __syncthreads();
    bf16* ob = xT + ((size_t)b * NPIX + n0) * NC + c0;
#pragma unroll
    for (int i = 0; i < 4; ++i) {
        int nn = tr + i * 16;
        ushort4 u;
        u.x = bfbits(T[tc4][nn]); u.y = bfbits(T[tc4 + 1][nn]);
        u.z = bfbits(T[tc4 + 2][nn]); u.w = bfbits(T[tc4 + 3][nn]);
        *reinterpret_cast<ushort4*>(ob + (size_t)nn * NC + tc4) = u;
    }
}

// convert qkv_w (512x256 f32) -> bf16
__global__ __launch_bounds__(256) void k_cvtw(const float* __restrict__ w, bf16* __restrict__ wb) {
    int idx = blockIdx.x * 256 + threadIdx.x;
    if (idx < 512 * 256) wb[idx] = __float2bfloat16(w[idx]);
}

// ---------------- MFMA GEMM: Out[b,o,n] = sum_k W[(b),o,k] * X[b,n,k]  (128x128 tile) ----------------
// T2 XOR-swizzle on LDS: 16B-unit column col8 stored at col8^(row&7) -> 2-way max on frag reads.
template <typename TOUT>
__global__ __launch_bounds__(256) void k_gemm_bf(const bf16* __restrict__ X, const bf16* __restrict__ Wm,
                                                 int wStride, TOUT* __restrict__ Out) {
    __shared__ __align__(16) short As[128 * 64];
    __shared__ __align__(16) short Bs[128 * 64];
    int nt = blockIdx.x, ot = blockIdx.y, b = blockIdx.z;
    int n0 = nt * 128, o0 = ot * 128;
    const bf16* xb = X + (size_t)b * NPIX * NC;
    const bf16* Wb = Wm + (size_t)b * wStride;
    int t = threadIdx.x;
    int wv = t >> 6, l = t & 63;
    int wr = wv >> 1, wc = wv & 1;
    f32x4 z4 = {0.f, 0.f, 0.f, 0.f};
    f32x4 acc[4][4];
#pragma unroll
    for (int m = 0; m < 4; ++m)
#pragma unroll
        for (int nf = 0; nf < 4; ++nf) acc[m][nf] = z4;
    for (int kc = 0; kc < 256; kc += 64) {
        __syncthreads();
#pragma unroll
        for (int i = 0; i < 4; ++i) {
            int blk = t + 256 * i;
            int r = blk >> 3, cb = blk & 7;
            int cbs = cb ^ (r & 7);
            *(short8v*)(As + r * 64 + cbs * 8) = *(const short8v*)(Wb + (size_t)(o0 + r) * NC + kc + cb * 8);
            *(short8v*)(Bs + r * 64 + cbs * 8) = *(const short8v*)(xb + (size_t)(n0 + r) * NC + kc + cb * 8);
        }
        __syncthreads();
#pragma unroll
        for (int kk = 0; kk < 2; ++kk) {
            int col8 = kk * 4 + (l >> 4);
            short8v av[4], bv[4];
#pragma unroll
            for (int m = 0; m < 4; ++m) {
                int row = wr * 64 + m * 16 + (l & 15);
                av[m] = *(const short8v*)(As + row * 64 + (col8 ^ (row & 7)) * 8);
            }
#pragma unroll
            for (int nf = 0; nf < 4; ++nf) {
                int row = wc * 64 + nf * 16 + (l & 15);
                bv[nf] = *(const short8v*)(Bs + row * 64 + (col8 ^ (row & 7)) * 8);
            }
#pragma unroll
            for (int m = 0; m < 4; ++m)
#pragma unroll
                for (int nf = 0; nf < 4; ++nf)
                    acc[m][nf] = __builtin_amdgcn_mfma_f32_16x16x32_bf16(av[m], bv[nf], acc[m][nf], 0, 0, 0);
        }
    }
    TOUT* ob = Out + (size_t)b * NC * NPIX;
#pragma unroll
    for (int m = 0; m < 4; ++m)
#pragma unroll
        for (int nf = 0; nf < 4; ++nf)
#pragma unroll
            for (int r = 0; r < 4; ++r) {
                int oo = o0 + wr * 64 + m * 16 + (l >> 4) * 4 + r;
                int nn = n0 + wc * 64 + nf * 16 + (l & 15);
                if constexpr (sizeof(TOUT) == 2)
                    ob[(size_t)oo * NPIX + nn] = __float2bfloat16(acc[m][nf][r]);
                else
                    ob[(size_t)oo * NPIX + nn] = acc[m][nf][r];
            }
}

// ---------------- Gram + fused dw3x3, register-direct ----------------
__device__ inline short8v dw8(const bf16* __restrict__ chan, int r, int cb,
                              const float* __restrict__ w, float& ks) {
    float v[3][10];
#pragma unroll
    for (int ri = 0; ri < 3; ++ri) {
        int r2 = r + ri - 1;
        if (r2 < 0 || r2 >= NH) {
#pragma unroll
            for (int j = 0; j < 10; ++j) v[ri][j] = 0.f;
        } else {
            const bf16* p = chan + (size_t)r2 * NW + cb;
            short8v m = *(const short8v*)p;
            v[ri][0] = (cb > 0) ? __bfloat162float(p[-1]) : 0.f;
#pragma unroll
            for (int j = 0; j < 8; ++j) v[ri][j + 1] = b2f(m[j]);
            v[ri][9] = (cb < 184) ? __bfloat162float(p[8]) : 0.f;
        }
    }
    short8v out;
#pragma unroll
    for (int j = 0; j < 8; ++j) {
        float a = 0.f;
#pragma unroll
        for (int ri = 0; ri < 3; ++ri) {
            a = fmaf(v[ri][j],     w[ri * 3 + 0], a);
            a = fmaf(v[ri][j + 1], w[ri * 3 + 1], a);
            a = fmaf(v[ri][j + 2], w[ri * 3 + 2], a);
        }
        ks = fmaf(a, a, ks);
        out[j] = (short)bfbits(a);
    }
    return out;
}

__global__ __launch_bounds__(256) void k_gram_dw(const bf16* __restrict__ qbf, const bf16* __restrict__ kraw,
                                                 const float* __restrict__ dwW,
                                                 float* __restrict__ gpart, float* __restrict__ ksum) {
    int chunk = blockIdx.x;
    int bh = blockIdx.y; int b = bh >> 3, h = bh & 7;
    const bf16* qb = qbf + ((size_t)b * NC + h * 32) * NPIX;
    const bf16* kb = kraw + ((size_t)b * NC + h * 32) * NPIX;
    __shared__ float sg[4][1024];
    __shared__ float ksh[32];
    int t = threadIdx.x;
    int wv = t >> 6, l = t & 63;
    int dlo = l & 15, kslot = l >> 4;
    float wA[9], wB[9];
#pragma unroll
    for (int i = 0; i < 9; ++i) {
        wA[i] = dwW[(h * 32 + dlo) * 9 + i];
        wB[i] = dwW[(h * 32 + dlo + 16) * 9 + i];
    }
    const bf16* q0 = qb + (size_t)dlo * NPIX;
    const bf16* q1 = qb + (size_t)(dlo + 16) * NPIX;
    const bf16* k0 = kb + (size_t)dlo * NPIX;
    const bf16* k1 = kb + (size_t)(dlo + 16) * NPIX;
    f32x4 z4 = {0.f, 0.f, 0.f, 0.f};
    f32x4 a00 = z4, a01 = z4, a10 = z4, a11 = z4;
    float ks0 = 0.f, ks1 = 0.f;
    int r0 = chunk * 8 + wv * 2;
#pragma unroll
    for (int rr = 0; rr < 2; ++rr) {
        int r = r0 + rr;
#pragma unroll
        for (int c0 = 0; c0 < 192; c0 += 32) {
            int cb = c0 + kslot * 8;
            short8v av0 = *(const short8v*)(q0 + (size_t)r * NW + cb);
            short8v av1 = *(const short8v*)(q1 + (size_t)r * NW + cb);
            short8v bv0 = dw8(k0, r, cb, wA, ks0);
            short8v bv1 = dw8(k1, r, cb, wB, ks1);
            a00 = __builtin_amdgcn_mfma_f32_16x16x32_bf16(av0, bv0, a00, 0, 0, 0);
            a01 = __builtin_amdgcn_mfma_f32_16x16x32_bf16(av0, bv1, a01, 0, 0, 0);
            a10 = __builtin_amdgcn_mfma_f32_16x16x32_bf16(av1, bv0, a10, 0, 0, 0);
            a11 = __builtin_amdgcn_mfma_f32_16x16x32_bf16(av1, bv1, a11, 0, 0, 0);
        }
    }
    if (t < 32) ksh[t] = 0.f;
#pragma unroll
    for (int j = 0; j < 4; ++j) {
        int dA = kslot * 4 + j, dB = 16 + kslot * 4 + j;
        sg[wv][dA * 32 + dlo]      = a00[j];
        sg[wv][dA * 32 + 16 + dlo] = a01[j];
        sg[wv][dB * 32 + dlo]      = a10[j];
        sg[wv][dB * 32 + 16 + dlo] = a11[j];
    }
    __syncthreads();
    float* gp = gpart + ((size_t)bh * GCH + chunk) * 1024;
#pragma unroll
    for (int i = 0; i < 4; ++i) {
        int e = t + 256 * i;
        gp[e] = sg[0][e] + sg[1][e] + sg[2][e] + sg[3][e];
    }
    atomicAdd(&ksh[dlo], ks0);
    atomicAdd(&ksh[dlo + 16], ks1);
    __syncthreads();
    if (t < 32) atomicAdd(&ksum[b * NC + h * 32 + t], ksh[t]);
}

// reduce partials + normalize + temperature + row softmax
__global__ __launch_bounds__(1024) void k_attn(const float* __restrict__ gpart, const float* __restrict__ qsum,
                                               const float* __restrict__ ksum, const float* __restrict__ temp,
                                               float* __restrict__ attn) {
    int bh = blockIdx.x;
    int b = bh >> 3, h = bh & 7;
    int t = threadIdx.x;
    int d = t >> 5, e = t & 31;
    float s = 0.f;
    for (int i = 0; i < GCH; ++i) s += gpart[((size_t)bh * GCH + i) * 1024 + t];
    float rq = 1.f / fmaxf(sqrtf(qsum[b * NC + h * 32 + d]), 1e-12f);
    float rk = 1.f / fmaxf(sqrtf(ksum[b * NC + h * 32 + e]), 1e-12f);
    s *= rq * rk * temp[h];
    float m = s;
#pragma unroll
    for (int off = 16; off; off >>= 1) m = fmaxf(m, __shfl_xor(m, off, 32));
    float ex = expf(s - m);
    float sum = ex;
#pragma unroll
    for (int off = 16; off; off >>= 1) sum += __shfl_xor(sum, off, 32);
    attn[(size_t)bh * 1024 + t] = ex / sum;
}

// fold proj into attn -> bf16
__global__ __launch_bounds__(256) void k_wfold(const float* __restrict__ proj, const float* __restrict__ attn,
                                               bf16* __restrict__ wfbf) {
    int o = blockIdx.x, b = blockIdx.y;
    int t = threadIdx.x;
    int h = t >> 5, e = t & 31;
    const float* ap = attn + (size_t)(b * 8 + h) * 1024 + e;
    const float* pp = proj + o * NC + h * 32;
    float acc = 0.f;
#pragma unroll
    for (int d = 0; d < 32; ++d) acc = fmaf(pp[d], ap[d * 32], acc);
    wfbf[((size_t)b * NC + o) * NC + t] = __float2bfloat16(acc);
}

// ---------------- dw3x3(vraw) + transpose -> v2T [b][n][e] bf16 ----------------
__global__ __launch_bounds__(256) void k_dwv(const bf16* __restrict__ vraw, const float* __restrict__ dwW,
                                             bf16* __restrict__ v2T) {
    int r = blockIdx.x;
    int cg = blockIdx.y;
    int b = blockIdx.z;
    __shared__ short s_v[3][32][204];     // cols 0..199 = global -4..195
    const bf16* vb = vraw + ((size_t)b * NC + cg * 32) * NPIX;
    int t = threadIdx.x;
    for (int idx = t; idx < 4800; idx += 256) {
        int ri = idx / 1600;
        int rem = idx - ri * 1600;
        int e = rem / 50, j = rem - e * 50;
        int gr = r + ri - 1;
        int gc0 = -4 + 4 * j;
        ushort4 u = make_ushort4(0, 0, 0, 0);
        if (gr >= 0 && gr < NH && gc0 >= 0 && gc0 + 3 < NW)
            u = *reinterpret_cast<const ushort4*>(vb + (size_t)e * NPIX + (size_t)gr * NW + gc0);
        *reinterpret_cast<ushort4*>(&s_v[ri][e][4 * j]) = u;
    }
    int e = t & 31;
    int wslot = t >> 5;
    float w9[9];
#pragma unroll
    for (int i = 0; i < 9; ++i) w9[i] = dwW[(256 + cg * 32 + e) * 9 + i];
    __syncthreads();
    bf16* ob = v2T + ((size_t)b * NPIX + (size_t)r * NW) * NC + cg * 32 + e;
#pragma unroll
    for (int wi = 0; wi < 24; ++wi) {
        int w = wslot + 8 * wi;
        int cbase = w + 3;                // staged col of (w-1)
        float a = 0.f;
#pragma unroll
        for (int ri = 0; ri < 3; ++ri) {
            a = fmaf(b2f(s_v[ri][e][cbase]),     w9[ri * 3 + 0], a);
            a = fmaf(b2f(s_v[ri][e][cbase + 1]), w9[ri * 3 + 1], a);
            a = fmaf(b2f(s_v[ri][e][cbase + 2]), w9[ri * 3 + 2], a);
        }
        ob[(size_t)w * NC] = __float2bfloat16(a);
    }
}

// ---------------- launcher ----------------

extern "C" void kernel_launch(void* const* d_in, const int* in_sizes, int n_in,
                              void* d_out, int out_size, void* d_ws, size_t ws_size,
                              hipStream_t stream) {
    (void)in_sizes; (void)n_in; (void)out_size;
    const float* x      = (const float*)d_in[0];
    const float* qkv_w  = (const float*)d_in[1];
    const float* qkv_cw = (const float*)d_in[2];
    const float* w5     = (const float*)d_in[3];
    const float* w7     = (const float*)d_in[4];
    const float* w9     = (const float*)d_in[5];
    const float* projw  = (const float*)d_in[6];
    const float* temp   = (const float*)d_in[7];

    // WS: [0:78.7M] kraw -> (dead) -> v2T ; [78.7M:] smalls
    const size_t OFF_SM    = 78675968;
    const size_t OFF_WBF   = OFF_SM;                    // 262,144
    const size_t OFF_QSUM  = OFF_SM + 262144;           // 4,096
    const size_t OFF_KSUM  = OFF_QSUM + 4096;           // 4,096
    const size_t OFF_GPART = OFF_KSUM + 4096;           // 3,145,728 (GCH=24)
    const size_t OFF_ATTN  = OFF_GPART + 3145728;       // 131,072
    const size_t OFF_WF    = OFF_ATTN + 131072;         // 524,288
    const size_t WS_NEED   = OFF_WF + 524288;           // 82,747,392
    if (ws_size < WS_NEED) return;

    char* ws = (char*)d_ws;
    bf16*  kraw  = (bf16*)ws;
    bf16*  v2T   = (bf16*)ws;
    bf16*  wbf   = (bf16*)(ws + OFF_WBF);
    float* qsum  = (float*)(ws + OFF_QSUM);
    float* ksum  = (float*)(ws + OFF_KSUM);
    float* gpart = (float*)(ws + OFF_GPART);
    float* attn  = (float*)(ws + OFF_ATTN);
    bf16*  wfbf  = (bf16*)(ws + OFF_WF);

    // OUT: xbf [0:75.5M] + qbf [75.5M:151M]; qbf dead after gram -> vraw there;
    // final out overwrites xbf+vraw (both dead by then).
    bf16*  xbf  = (bf16*)d_out;
    bf16*  qbf  = (bf16*)((char*)d_out + 75497472);
    bf16*  vraw = (bf16*)((char*)d_out + 75497472);
    float* out  = (float*)d_out;

    hipMemsetAsync(ws + OFF_QSUM, 0, 8192, stream);   // qsum + ksum

    // wavelet query path: single fused kernel x -> qbf + qsum
    k_wave<<<dim3(3, 6, NB * NC), 256, 0, stream>>>(x, w5, w7, w9, qbf, qsum);

    // shared GEMM inputs
    k_xpose<<<dim3(576, 4, NB), 256, 0, stream>>>(x, xbf);
    k_cvtw<<<512, 256, 0, stream>>>(qkv_w, wbf);

    // k path
    k_gemm_bf<bf16><<<dim3(288, 2, NB), 256, 0, stream>>>(xbf, wbf, 0, kraw);
    k_gram_dw<<<dim3(GCH, 32), 256, 0, stream>>>(qbf, kraw, qkv_cw, gpart, ksum);

    k_attn<<<32, 1024, 0, stream>>>(gpart, qsum, ksum, temp, attn);
    k_wfold<<<dim3(256, NB), 256, 0, stream>>>(projw, attn, wfbf);

    // v path
    k_gemm_bf<bf16><<<dim3(288, 2, NB), 256, 0, stream>>>(xbf, wbf + 256 * 256, 0, vraw);
    k_dwv<<<dim3(NH, 8, NB), 256, 0, stream>>>(vraw, qkv_cw, v2T);
    k_gemm_bf<float><<<dim3(288, 2, NB), 256, 0, stream>>>(v2T, wfbf, 65536, out);
}